// Round 10
// baseline (738.861 us; speedup 1.0000x reference)
//
#include <hip/hip_runtime.h>
#include <hip/hip_bf16.h>
#include <cstddef>

// Problem constants
#define BB   8
#define CIN  16
#define COUT 16
#define TT   32
#define HH   16
#define WW   16
#define DIN  4096
#define DOUT 4096
#define NH   4
#define DH   1024
#define SPAT 8192            // T*H*W
#define NSEQ 256             // B*T

typedef __attribute__((ext_vector_type(8))) short  bf16x8;
typedef __attribute__((ext_vector_type(4))) float  f32x4;
typedef __attribute__((ext_vector_type(4))) unsigned short us4;
typedef unsigned short ushort_t;
typedef unsigned long long u64_t;

static __device__ __forceinline__ ushort_t f2bf(float f) {
    union { float f; unsigned u; } v; v.f = f;
    unsigned r = (v.u + 0x7fffu + ((v.u >> 16) & 1u)) >> 16;
    return (ushort_t)r;
}
static __device__ __forceinline__ float bf2f(ushort_t u) {
    union { unsigned u; float f; } v; v.u = ((unsigned)u) << 16;
    return v.f;
}

// ---------------------------------------------------------------------------
// pack x (B,16,32,16,16) fp32 -> xt[n=b*32+t][k=c*256+hw] bf16
// ---------------------------------------------------------------------------
__global__ void pack_xt_kernel(const float* __restrict__ x, ushort_t* __restrict__ xt) {
    int idx = blockIdx.x * 256 + threadIdx.x;          // 0 .. 262143 (4 elems each)
    int n = idx >> 10, k4 = (idx & 1023) * 4;
    int b = n >> 5, t = n & 31, c = k4 >> 8, hw = k4 & 255;
    f32x4 f = *(const f32x4*)&x[(((size_t)(b * CIN + c) * TT + t)) * 256 + hw];
    us4 o;
    #pragma unroll
    for (int i = 0; i < 4; ++i) o[i] = f2bf(f[i]);
    *(us4*)&xt[(size_t)n * DIN + k4] = o;
}

// ---------------------------------------------------------------------------
// MFMA GEMM, single M-tile: C[256][N] = A[256][K](bf16) * B[N][K]^T(fp32) + bias
// BM=256 BN=64 BK=64, 256 threads (4 waves), double-buffered LDS.
// B read exactly once from HBM (fp32, converted on the fly).
// ---------------------------------------------------------------------------
template<bool OUT_BF16>
__global__ __launch_bounds__(256, 2)
void mfma_gemm_kernel(const ushort_t* __restrict__ A, const float* __restrict__ B,
                      const float* __restrict__ bias, void* __restrict__ C,
                      int N, int K) {
    __shared__ ushort_t Al[2][256][64];   // 64 KB
    __shared__ ushort_t Bl[2][64][64];    // 16 KB
    int tid  = threadIdx.x;
    int lane = tid & 63;
    int wv   = tid >> 6;       // 0..3 : wave owns rows [wv*64, wv*64+64)
    int n0 = blockIdx.x * 64;

    f32x4 acc[4][4];
    #pragma unroll
    for (int i = 0; i < 4; ++i)
        #pragma unroll
        for (int j = 0; j < 4; ++j) acc[i][j] = (f32x4){0.f, 0.f, 0.f, 0.f};

    auto stageA = [&](int buf, int k0) {
        #pragma unroll
        for (int q = 0; q < 8; ++q) {
            int row = wv * 64 + q * 8 + (lane >> 3);
            const ushort_t* g = A + (size_t)row * K + k0 + (lane & 7) * 8;
            __builtin_amdgcn_global_load_lds(
                (const __attribute__((address_space(1))) void*)g,
                (__attribute__((address_space(3))) void*)&Al[buf][wv * 64 + q * 8][0],
                16, 0, 0);
        }
    };
    auto stageB = [&](int buf, int k0) {
        int r = tid >> 2;               // 0..63
        int cs = (tid & 3) * 16;        // 0,16,32,48
        const float* g = B + (size_t)(n0 + r) * K + k0 + cs;
        f32x4 f0 = *(const f32x4*)(g);
        f32x4 f1 = *(const f32x4*)(g + 4);
        f32x4 f2 = *(const f32x4*)(g + 8);
        f32x4 f3 = *(const f32x4*)(g + 12);
        union { ushort_t u[16]; bf16x8 v[2]; } pk;
        #pragma unroll
        for (int i = 0; i < 4; ++i) {
            pk.u[i]      = f2bf(f0[i]);
            pk.u[4 + i]  = f2bf(f1[i]);
            pk.u[8 + i]  = f2bf(f2[i]);
            pk.u[12 + i] = f2bf(f3[i]);
        }
        *(bf16x8*)&Bl[buf][r][cs]     = pk.v[0];
        *(bf16x8*)&Bl[buf][r][cs + 8] = pk.v[1];
    };
    auto compute = [&](int buf) {
        #pragma unroll
        for (int ks = 0; ks < 2; ++ks) {
            bf16x8 af[4], bfr[4];
            #pragma unroll
            for (int i = 0; i < 4; ++i)
                af[i] = *(const bf16x8*)&Al[buf][wv * 64 + i * 16 + (lane & 15)][ks * 32 + (lane >> 4) * 8];
            #pragma unroll
            for (int j = 0; j < 4; ++j)
                bfr[j] = *(const bf16x8*)&Bl[buf][j * 16 + (lane & 15)][ks * 32 + (lane >> 4) * 8];
            #pragma unroll
            for (int i = 0; i < 4; ++i)
                #pragma unroll
                for (int j = 0; j < 4; ++j)
                    acc[i][j] = __builtin_amdgcn_mfma_f32_16x16x32_bf16(af[i], bfr[j], acc[i][j], 0, 0, 0);
        }
    };

    stageA(0, 0); stageB(0, 0);
    __syncthreads();
    int nk = K / 64;
    int cur = 0;
    for (int t = 0; t < nk; ++t) {
        if (t + 1 < nk) { stageA(cur ^ 1, (t + 1) * 64); stageB(cur ^ 1, (t + 1) * 64); }
        compute(cur);
        __syncthreads();
        cur ^= 1;
    }

    #pragma unroll
    for (int i = 0; i < 4; ++i) {
        int row = wv * 64 + i * 16 + (lane >> 4) * 4;
        #pragma unroll
        for (int j = 0; j < 4; ++j) {
            int col = n0 + j * 16 + (lane & 15);
            float bv = bias[col];
            #pragma unroll
            for (int r = 0; r < 4; ++r) {
                float v = acc[i][j][r] + bv;
                if constexpr (OUT_BF16) ((ushort_t*)C)[(size_t)(row + r) * N + col] = f2bf(v);
                else                    ((float*)C)[(size_t)(row + r) * N + col] = v;
            }
        }
    }
}

// ---------------------------------------------------------------------------
// Persistent sLSTM, data-as-flag sync (single LLC round trip per step):
//  - h element = u64 slot: low32 = (lo_bf16<<16 | hi_bf16), high32 = tag (t+1).
//    One relaxed agent-scope atomic store publishes value+flag atomically;
//    consumers spin on the slots they consume (tag == t). No fences, no vmcnt
//    drain, no flag array. hfr zeroed per call (tags 1..32 never match 0).
//  - R (fp32) staged directly into LDS in MFMA fragment order, once.
//  - hs history is NOT written here; combine reconstructs h from the slots.
// grid: 256 blocks = head(4) x ochunk(64 of 16 o's), 256 threads, 1 block/CU.
// wave = K-chunk (8 ks each), all 4 gates per wave; partial-gh reduce in LDS.
// ---------------------------------------------------------------------------
__global__ __launch_bounds__(256, 1)
void lstm_persist_kernel(const float* __restrict__ R,       // [4][4][1024][1024] fp32
                         const float* __restrict__ Gx,      // [256][16384]
                         u64_t* __restrict__ hfr) {         // [32][4][32][8][32] u64, zeroed
    __shared__ ushort_t Rl[4][32][64 * 8];   // [gate][ks][lane*8] = 128 KB
    __shared__ float gh_p[4][4][16][8];      // [wave][gate][o_l][b] = 8 KB

    int tid  = threadIdx.x;
    int lane = tid & 63;
    int w    = tid >> 6;               // wave = K-chunk (ks in [w*8, w*8+8))
    int head = blockIdx.x >> 6;
    int oc   = blockIdx.x & 63;

    // ---- stage R slice fp32 -> bf16 LDS in fragment order, once ----
    for (int n = 0; n < 64; ++n) {
        int g = n >> 4, r = n & 15;
        const float* src = R + ((size_t)((head * 4 + g) * DH + oc * 16 + r)) * DH + tid * 4;
        f32x4 f = *(const f32x4*)src;
        int k0 = tid * 4;
        int ks = k0 >> 5;
        int kI = (k0 >> 3) & 3;
        int e8 = k0 & 7;               // 0 or 4
        union { ushort_t u[4]; u64_t q; } pk;
        #pragma unroll
        for (int e = 0; e < 4; ++e) pk.u[e] = f2bf(f[e]);
        *(u64_t*)&Rl[g][ks][((kI << 4) | r) * 8 + e8] = pk.q;
    }

    int arow = lane & 15;          // packed-B column (part,bb); also D column
    int part = arow >> 3;          // 0: hi half of h, 1: lo half
    int bb   = arow & 7;           // batch
    int kseg = lane >> 4;          // 0..3

    // gate-phase identity (tid < 128)
    int gb  = tid >> 4;            // batch
    int gol = tid & 15;            // o_local
    int gd  = head * DH + oc * 16 + gol;
    int o_h = oc * 16 + gol;       // o within head (= k index for next step)
    size_t hslot = (size_t)head * 8192 + (o_h >> 5) * 256 + gb * 32 + (o_h & 31);
    float c_r = 0.f, n_r = 0.f, m_r = 0.f;

    __syncthreads();

    for (int t = 0; t < TT; ++t) {
        // prefetch this step's Gx (h-independent) before any waiting
        float gx0 = 0.f, gx1 = 0.f, gx2 = 0.f, gx3 = 0.f;
        if (tid < 128) {
            size_t gxoff = ((size_t)(gb * TT + t)) * (4 * DOUT) + gd;
            gx0 = Gx[gxoff];
            gx1 = Gx[gxoff + DOUT];
            gx2 = Gx[gxoff + 2 * DOUT];
            gx3 = Gx[gxoff + 3 * DOUT];
        }

        if (t > 0) {
            // spin directly on the h slots this wave consumes (tag == t)
            const u64_t* hb = hfr + (size_t)(t - 1) * 32768 + (size_t)head * 8192
                              + bb * 32 + kseg * 8;
            bf16x8 hf[8];
            #pragma unroll
            for (int j = 0; j < 8; ++j) {
                const u64_t* p = hb + (size_t)(w * 8 + j) * 256;
                u64_t q[8];
                int ok;
                do {
                    ok = 1;
                    #pragma unroll
                    for (int e = 0; e < 8; ++e)
                        q[e] = __hip_atomic_load(p + e, __ATOMIC_RELAXED,
                                                 __HIP_MEMORY_SCOPE_AGENT);
                    #pragma unroll
                    for (int e = 0; e < 8; ++e)
                        ok &= ((unsigned)(q[e] >> 32) == (unsigned)t);
                } while (!__all(ok));
                union { ushort_t u[8]; bf16x8 v; } fr;
                #pragma unroll
                for (int e = 0; e < 8; ++e) {
                    unsigned v32 = (unsigned)q[e];
                    fr.u[e] = part ? (ushort_t)(v32 >> 16) : (ushort_t)(v32 & 0xffffu);
                }
                hf[j] = fr.v;
            }

            f32x4 acc[4];
            #pragma unroll
            for (int g = 0; g < 4; ++g) acc[g] = (f32x4){0.f, 0.f, 0.f, 0.f};
            #pragma unroll
            for (int g = 0; g < 4; ++g)
                #pragma unroll
                for (int j = 0; j < 8; ++j) {
                    bf16x8 a = *(const bf16x8*)&Rl[g][w * 8 + j][lane * 8];
                    acc[g] = __builtin_amdgcn_mfma_f32_16x16x32_bf16(a, hf[j], acc[g], 0, 0, 0);
                }
            // fold hi+lo halves (partner column = col^8 -> lane^8)
            #pragma unroll
            for (int g = 0; g < 4; ++g)
                #pragma unroll
                for (int r = 0; r < 4; ++r)
                    acc[g][r] += __shfl_xor(acc[g][r], 8, 64);
            // D layout: col = lane&15, row = kseg*4 + r
            if (part == 0) {
                int orow0 = kseg * 4;
                #pragma unroll
                for (int g = 0; g < 4; ++g)
                    #pragma unroll
                    for (int r = 0; r < 4; ++r)
                        gh_p[w][g][orow0 + r][bb] = acc[g][r];
            }
        } else {
            for (int i = tid; i < 4 * 4 * 16 * 8; i += 256)
                ((float*)gh_p)[i] = 0.f;
        }
        __syncthreads();

        if (tid < 128) {
            float ip = gx0 +
                gh_p[0][0][gol][gb] + gh_p[1][0][gol][gb] + gh_p[2][0][gol][gb] + gh_p[3][0][gol][gb];
            float fp = gx1 +
                gh_p[0][1][gol][gb] + gh_p[1][1][gol][gb] + gh_p[2][1][gol][gb] + gh_p[3][1][gol][gb];
            float zp = gx2 +
                gh_p[0][2][gol][gb] + gh_p[1][2][gol][gb] + gh_p[2][2][gol][gb] + gh_p[3][2][gol][gb];
            float op = gx3 +
                gh_p[0][3][gol][gb] + gh_p[1][3][gol][gb] + gh_p[2][3][gol][gb] + gh_p[3][3][gol][gb];
            float mn = fmaxf(fp + m_r, ip);
            float iv = expf(ip - mn);
            float fv = expf(fp + m_r - mn);
            c_r = fv * c_r + iv * tanhf(zp);
            n_r = fv * n_r + iv;
            float sig = 1.f / (1.f + expf(-op));
            float hv = sig * c_r / n_r;
            m_r = mn;
            unsigned hi = f2bf(hv);
            unsigned lo = f2bf(hv - bf2f((ushort_t)hi));
            u64_t q = ((u64_t)(unsigned)(t + 1) << 32) | (u64_t)(hi | (lo << 16));
            __hip_atomic_store(&hfr[(size_t)t * 32768 + hslot], q,
                               __ATOMIC_RELAXED, __HIP_MEMORY_SCOPE_AGENT);
        }
        __syncthreads();   // protects gh_p reuse across steps
    }
}

// ---------------------------------------------------------------------------
// conv3d 3x3x3 pad=1: one block per (b,t); LDS-staged input slice + weights.
// ---------------------------------------------------------------------------
__global__ __launch_bounds__(256)
void conv3d_kernel(const float* __restrict__ in, const float* __restrict__ w,
                   const float* __restrict__ bias, float* __restrict__ out, int relu) {
    __shared__ float xin[CIN][3][256];      // 48 KB
    __shared__ float wl[CIN][27][16];       // 27 KB, o-fastest
    int b = blockIdx.x >> 5, t = blockIdx.x & 31;
    int tid = threadIdx.x;

    for (int i = tid; i < CIN * 27 * 16; i += 256) {
        int o = i & 15, r = i >> 4;
        int k = r % 27, ci = r / 27;
        wl[ci][k][o] = w[(size_t)(o * CIN + ci) * 27 + k];
    }
    for (int i = tid; i < CIN * 3 * 256; i += 256) {
        int hw = i & 255, r = i >> 8;
        int kt = r % 3, ci = r / 3;
        int tt = t + kt - 1;
        xin[ci][kt][hw] = ((unsigned)tt < TT)
            ? in[((size_t)(b * CIN + ci) * TT + tt) * 256 + hw] : 0.f;
    }
    __syncthreads();

    int h = tid >> 4, wx = tid & 15;
    f32x4 a0 = *(const f32x4*)&bias[0];
    f32x4 a1 = *(const f32x4*)&bias[4];
    f32x4 a2 = *(const f32x4*)&bias[8];
    f32x4 a3 = *(const f32x4*)&bias[12];

    for (int ci = 0; ci < CIN; ++ci) {
        #pragma unroll
        for (int kt = 0; kt < 3; ++kt) {
            #pragma unroll
            for (int kh = 0; kh < 3; ++kh) {
                int h2 = h + kh - 1;
                if ((unsigned)h2 >= HH) continue;
                #pragma unroll
                for (int kw = 0; kw < 3; ++kw) {
                    int w2 = wx + kw - 1;
                    if ((unsigned)w2 >= WW) continue;
                    float xv = xin[ci][kt][h2 * 16 + w2];
                    int k = kt * 9 + kh * 3 + kw;
                    f32x4 w0 = *(const f32x4*)&wl[ci][k][0];
                    f32x4 w1 = *(const f32x4*)&wl[ci][k][4];
                    f32x4 w2v = *(const f32x4*)&wl[ci][k][8];
                    f32x4 w3 = *(const f32x4*)&wl[ci][k][12];
                    a0 += xv * w0; a1 += xv * w1; a2 += xv * w2v; a3 += xv * w3;
                }
            }
        }
    }
    float accs[16];
    #pragma unroll
    for (int i = 0; i < 4; ++i) { accs[i] = a0[i]; accs[4+i] = a1[i]; accs[8+i] = a2[i]; accs[12+i] = a3[i]; }
    #pragma unroll
    for (int o = 0; o < 16; ++o) {
        float v = accs[o];
        if (relu) v = fmaxf(v, 0.f);
        out[((size_t)(b * COUT + o) * TT + t) * 256 + tid] = v;
    }
}

// ---------------------------------------------------------------------------
// instance norm over (T,H,W) per (b,c) + relu, in place. 128 blocks.
// ---------------------------------------------------------------------------
__global__ void inorm_relu_kernel(float* __restrict__ y) {
    __shared__ float s1[256], s2[256];
    float* p = y + (size_t)blockIdx.x * SPAT;
    float sum = 0.f, sq = 0.f;
    for (int i = threadIdx.x; i < SPAT; i += 256) {
        float v = p[i];
        sum += v; sq += v * v;
    }
    s1[threadIdx.x] = sum; s2[threadIdx.x] = sq;
    __syncthreads();
    for (int s = 128; s > 0; s >>= 1) {
        if (threadIdx.x < s) { s1[threadIdx.x] += s1[threadIdx.x + s]; s2[threadIdx.x] += s2[threadIdx.x + s]; }
        __syncthreads();
    }
    float mu = s1[0] / (float)SPAT;
    float var = s2[0] / (float)SPAT - mu * mu;
    float rs = rsqrtf(var + 1e-5f);
    for (int i = threadIdx.x; i < SPAT; i += 256) {
        float v = (p[i] - mu) * rs;
        p[i] = fmaxf(v, 0.f);
    }
}

// ---------------------------------------------------------------------------
// final combine: h reconstructed from the u64 slots (bf2f(hi)+bf2f(lo))
// ---------------------------------------------------------------------------
__global__ void combine_kernel(const u64_t* __restrict__ hfr,
                               const float* __restrict__ out3d,
                               const float* __restrict__ attn_w,
                               const float* __restrict__ attn_b,
                               float* __restrict__ out) {
    int idx = blockIdx.x * 256 + threadIdx.x;
    int hw = idx & 255;
    int t  = (idx >> 8) & 31;
    int b  = idx >> 13;
    float dot = attn_b[0];
    float sv[16], ov[16];
    #pragma unroll
    for (int ch = 0; ch < 16; ++ch) {
        int d = ch * 256 + hw;
        int head = d >> 10, o_h = d & 1023;
        size_t slot = (size_t)t * 32768 + (size_t)head * 8192
                    + (o_h >> 5) * 256 + b * 32 + (o_h & 31);
        unsigned v32 = (unsigned)hfr[slot];
        float s = bf2f((ushort_t)(v32 & 0xffffu)) + bf2f((ushort_t)(v32 >> 16));
        float o3 = out3d[(((size_t)(b * COUT + ch) * TT + t)) * 256 + hw];
        sv[ch] = s; ov[ch] = o3;
        dot += attn_w[ch] * s + attn_w[16 + ch] * o3;
    }
    float alpha = 1.f / (1.f + expf(-dot));
    #pragma unroll
    for (int ch = 0; ch < 16; ++ch) {
        out[(((size_t)(b * COUT + ch) * TT + t)) * 256 + hw] =
            alpha * ov[ch] + (1.f - alpha) * sv[ch];
    }
}

// ---------------------------------------------------------------------------
extern "C" void kernel_launch(void* const* d_in, const int* in_sizes, int n_in,
                              void* d_out, int out_size, void* d_ws, size_t ws_size,
                              hipStream_t stream) {
    const float* x      = (const float*)d_in[0];
    const float* c1_w   = (const float*)d_in[1];
    const float* c1_b   = (const float*)d_in[2];
    const float* c2_w   = (const float*)d_in[3];
    const float* c2_b   = (const float*)d_in[4];
    const float* c3_w   = (const float*)d_in[5];
    const float* c3_b   = (const float*)d_in[6];
    const float* pre_w  = (const float*)d_in[7];
    const float* pre_b  = (const float*)d_in[8];
    const float* lstm_W = (const float*)d_in[9];
    const float* lstm_b = (const float*)d_in[10];
    const float* lstm_R = (const float*)d_in[11];
    const float* attn_w = (const float*)d_in[12];
    const float* attn_b = (const float*)d_in[13];
    float* out = (float*)d_out;

    // workspace carve (all 16B aligned; hfr 8B-aligned u64 region first-class)
    float* wsf = (float*)d_ws;
    float* y1    = wsf;                // 1048576 f32
    float* y2    = y1 + 1048576;       // 1048576 f32
    float* out3d = y2 + 1048576;       // 1048576 f32
    float* Gx    = out3d + 1048576;    // 4194304 f32
    u64_t* hfr   = (u64_t*)(Gx + 4194304);        // 1048576 u64 (8 MB)
    ushort_t* xt   = (ushort_t*)(hfr + 1048576);  // 1048576 bf16
    ushort_t* xs2b = xt + 1048576;                // 1048576 bf16

    // reset h slot tags (tags 1..32 never match 0) — required across replays
    hipMemsetAsync(hfr, 0, 1048576 * sizeof(u64_t), stream);

    // pack x -> bf16 sequence layout
    pack_xt_kernel<<<1024, 256, 0, stream>>>(x, xt);

    // convs
    conv3d_kernel<<<256, 256, 0, stream>>>(x, c1_w, c1_b, y1, 0);
    inorm_relu_kernel<<<128, 256, 0, stream>>>(y1);
    conv3d_kernel<<<256, 256, 0, stream>>>(y1, c2_w, c2_b, y2, 1);
    conv3d_kernel<<<256, 256, 0, stream>>>(y2, c3_w, c3_b, out3d, 1);

    // pre-projection -> xs2 (bf16); gate projection -> Gx (fp32); B read once
    mfma_gemm_kernel<true><<<DOUT / 64, 256, 0, stream>>>(xt, pre_w, pre_b, xs2b, DOUT, DIN);
    mfma_gemm_kernel<false><<<4 * DOUT / 64, 256, 0, stream>>>(xs2b, lstm_W, lstm_b, Gx, 4 * DOUT, DOUT);

    // recurrence: one persistent kernel, data-as-flag sync
    lstm_persist_kernel<<<256, 256, 0, stream>>>(lstm_R, Gx, hfr);

    // combine (reads h from slots)
    combine_kernel<<<256, 256, 0, stream>>>(hfr, out3d, attn_w, attn_b, out);
}

// Round 11
// 660.444 us; speedup vs baseline: 1.1187x; 1.1187x over previous
//
#include <hip/hip_runtime.h>
#include <hip/hip_bf16.h>
#include <cstddef>

// Problem constants
#define BB   8
#define CIN  16
#define COUT 16
#define TT   32
#define HH   16
#define WW   16
#define DIN  4096
#define DOUT 4096
#define NH   4
#define DH   1024
#define SPAT 8192            // T*H*W
#define NSEQ 256             // B*T

typedef __attribute__((ext_vector_type(8))) short  bf16x8;
typedef __attribute__((ext_vector_type(4))) float  f32x4;
typedef __attribute__((ext_vector_type(4))) unsigned short us4;
typedef unsigned short ushort_t;
typedef unsigned long long u64_t;

static __device__ __forceinline__ ushort_t f2bf(float f) {
    union { float f; unsigned u; } v; v.f = f;
    unsigned r = (v.u + 0x7fffu + ((v.u >> 16) & 1u)) >> 16;
    return (ushort_t)r;
}
static __device__ __forceinline__ float bf2f(ushort_t u) {
    union { unsigned u; float f; } v; v.u = ((unsigned)u) << 16;
    return v.f;
}

// ---------------------------------------------------------------------------
// pack x (B,16,32,16,16) fp32 -> xt[n=b*32+t][k=c*256+hw] bf16
// ---------------------------------------------------------------------------
__global__ void pack_xt_kernel(const float* __restrict__ x, ushort_t* __restrict__ xt) {
    int idx = blockIdx.x * 256 + threadIdx.x;          // 0 .. 262143 (4 elems each)
    int n = idx >> 10, k4 = (idx & 1023) * 4;
    int b = n >> 5, t = n & 31, c = k4 >> 8, hw = k4 & 255;
    f32x4 f = *(const f32x4*)&x[(((size_t)(b * CIN + c) * TT + t)) * 256 + hw];
    us4 o;
    #pragma unroll
    for (int i = 0; i < 4; ++i) o[i] = f2bf(f[i]);
    *(us4*)&xt[(size_t)n * DIN + k4] = o;
}

// ---------------------------------------------------------------------------
// pack conv weights (O,CI,3,3,3) -> cw[(ci*27+k)*16+o] (o fastest, fp32)
// grid 27 x 256 = 6912 threads
// ---------------------------------------------------------------------------
__global__ void pack_cw_kernel(const float* __restrict__ w, float* __restrict__ cw) {
    int i = blockIdx.x * 256 + threadIdx.x;   // 0..6911
    int o = i & 15, r = i >> 4;               // r = ci*27 + k
    int k = r % 27, ci = r / 27;
    cw[i] = w[(size_t)(o * CIN + ci) * 27 + k];
}

// ---------------------------------------------------------------------------
// MFMA GEMM, single M-tile: C[256][N] = A[256][K](bf16) * B[N][K]^T(fp32) + bias
// BM=256 BN=64 BK=64, 256 threads (4 waves), double-buffered LDS. B read once.
// ---------------------------------------------------------------------------
template<bool OUT_BF16>
__global__ __launch_bounds__(256, 2)
void mfma_gemm_kernel(const ushort_t* __restrict__ A, const float* __restrict__ B,
                      const float* __restrict__ bias, void* __restrict__ C,
                      int N, int K) {
    __shared__ ushort_t Al[2][256][64];   // 64 KB
    __shared__ ushort_t Bl[2][64][64];    // 16 KB
    int tid  = threadIdx.x;
    int lane = tid & 63;
    int wv   = tid >> 6;       // 0..3 : wave owns rows [wv*64, wv*64+64)
    int n0 = blockIdx.x * 64;

    f32x4 acc[4][4];
    #pragma unroll
    for (int i = 0; i < 4; ++i)
        #pragma unroll
        for (int j = 0; j < 4; ++j) acc[i][j] = (f32x4){0.f, 0.f, 0.f, 0.f};

    auto stageA = [&](int buf, int k0) {
        #pragma unroll
        for (int q = 0; q < 8; ++q) {
            int row = wv * 64 + q * 8 + (lane >> 3);
            const ushort_t* g = A + (size_t)row * K + k0 + (lane & 7) * 8;
            __builtin_amdgcn_global_load_lds(
                (const __attribute__((address_space(1))) void*)g,
                (__attribute__((address_space(3))) void*)&Al[buf][wv * 64 + q * 8][0],
                16, 0, 0);
        }
    };
    auto stageB = [&](int buf, int k0) {
        int r = tid >> 2;               // 0..63
        int cs = (tid & 3) * 16;        // 0,16,32,48
        const float* g = B + (size_t)(n0 + r) * K + k0 + cs;
        f32x4 f0 = *(const f32x4*)(g);
        f32x4 f1 = *(const f32x4*)(g + 4);
        f32x4 f2 = *(const f32x4*)(g + 8);
        f32x4 f3 = *(const f32x4*)(g + 12);
        union { ushort_t u[16]; bf16x8 v[2]; } pk;
        #pragma unroll
        for (int i = 0; i < 4; ++i) {
            pk.u[i]      = f2bf(f0[i]);
            pk.u[4 + i]  = f2bf(f1[i]);
            pk.u[8 + i]  = f2bf(f2[i]);
            pk.u[12 + i] = f2bf(f3[i]);
        }
        *(bf16x8*)&Bl[buf][r][cs]     = pk.v[0];
        *(bf16x8*)&Bl[buf][r][cs + 8] = pk.v[1];
    };
    auto compute = [&](int buf) {
        #pragma unroll
        for (int ks = 0; ks < 2; ++ks) {
            bf16x8 af[4], bfr[4];
            #pragma unroll
            for (int i = 0; i < 4; ++i)
                af[i] = *(const bf16x8*)&Al[buf][wv * 64 + i * 16 + (lane & 15)][ks * 32 + (lane >> 4) * 8];
            #pragma unroll
            for (int j = 0; j < 4; ++j)
                bfr[j] = *(const bf16x8*)&Bl[buf][j * 16 + (lane & 15)][ks * 32 + (lane >> 4) * 8];
            #pragma unroll
            for (int i = 0; i < 4; ++i)
                #pragma unroll
                for (int j = 0; j < 4; ++j)
                    acc[i][j] = __builtin_amdgcn_mfma_f32_16x16x32_bf16(af[i], bfr[j], acc[i][j], 0, 0, 0);
        }
    };

    stageA(0, 0); stageB(0, 0);
    __syncthreads();
    int nk = K / 64;
    int cur = 0;
    for (int t = 0; t < nk; ++t) {
        if (t + 1 < nk) { stageA(cur ^ 1, (t + 1) * 64); stageB(cur ^ 1, (t + 1) * 64); }
        compute(cur);
        __syncthreads();
        cur ^= 1;
    }

    #pragma unroll
    for (int i = 0; i < 4; ++i) {
        int row = wv * 64 + i * 16 + (lane >> 4) * 4;
        #pragma unroll
        for (int j = 0; j < 4; ++j) {
            int col = n0 + j * 16 + (lane & 15);
            float bv = bias[col];
            #pragma unroll
            for (int r = 0; r < 4; ++r) {
                float v = acc[i][j][r] + bv;
                if constexpr (OUT_BF16) ((ushort_t*)C)[(size_t)(row + r) * N + col] = f2bf(v);
                else                    ((float*)C)[(size_t)(row + r) * N + col] = v;
            }
        }
    }
}

// ---------------------------------------------------------------------------
// Persistent sLSTM (best-known sync, R8-style):
//  - R (fp32) staged directly into LDS in MFMA fragment order, once.
//  - h via hfr u32 slots [t][head][ks][b][k'] = (lo<<16|hi) bf16 pair; relaxed
//    agent atomics (LLC-coherent, no cache-wide fences).
//  - flags[t][head][oc]: tid0 stores after __syncthreads (vmcnt drained);
//    consumers poll the 64 flags of their head with one coalesced lane-load.
// grid: 256 blocks = head(4) x ochunk(64 of 16 o's), 256 threads, 1 block/CU.
// wave = K-chunk (8 ks each), all 4 gates per wave; partial-gh reduce in LDS.
// ---------------------------------------------------------------------------
__global__ __launch_bounds__(256, 1)
void lstm_persist_kernel(const float* __restrict__ R,       // [4][4][1024][1024] fp32
                         const float* __restrict__ Gx,      // [256][16384]
                         unsigned* __restrict__ hfr,        // [32][4][32][8][32] u32
                         float* __restrict__ hs,            // [8][32][4096] f32
                         int* __restrict__ flags) {         // [32][4][64], zeroed
    __shared__ ushort_t Rl[4][32][64 * 8];   // [gate][ks][lane*8] = 128 KB
    __shared__ float gh_p[4][4][16][8];      // [wave][gate][o_l][b] = 8 KB

    int tid  = threadIdx.x;
    int lane = tid & 63;
    int w    = tid >> 6;               // wave = K-chunk (ks in [w*8, w*8+8))
    int head = blockIdx.x >> 6;
    int oc   = blockIdx.x & 63;

    // ---- stage R slice fp32 -> bf16 LDS in fragment order, once ----
    for (int n = 0; n < 64; ++n) {
        int g = n >> 4, r = n & 15;
        const float* src = R + ((size_t)((head * 4 + g) * DH + oc * 16 + r)) * DH + tid * 4;
        f32x4 f = *(const f32x4*)src;
        int k0 = tid * 4;
        int ks = k0 >> 5;
        int kI = (k0 >> 3) & 3;
        int e8 = k0 & 7;               // 0 or 4
        union { ushort_t u[4]; u64_t q; } pk;
        #pragma unroll
        for (int e = 0; e < 4; ++e) pk.u[e] = f2bf(f[e]);
        *(u64_t*)&Rl[g][ks][((kI << 4) | r) * 8 + e8] = pk.q;
    }

    int arow = lane & 15;          // packed-B column (part,bb); also D column
    int part = arow >> 3;          // 0: hi half of h, 1: lo half
    int bb   = arow & 7;           // batch
    int kseg = lane >> 4;          // 0..3

    // gate-phase identity (tid < 128)
    int gb  = tid >> 4;            // batch
    int gol = tid & 15;            // o_local
    int gd  = head * DH + oc * 16 + gol;
    int o_h = oc * 16 + gol;       // o within head (= k index for next step)
    unsigned hslot = ((unsigned)head * 32 + (o_h >> 5)) * 256 + gb * 32 + (o_h & 31);
    float c_r = 0.f, n_r = 0.f, m_r = 0.f;

    __syncthreads();

    for (int t = 0; t < TT; ++t) {
        // prefetch this step's Gx (h-independent) before the flag wait
        float gx0 = 0.f, gx1 = 0.f, gx2 = 0.f, gx3 = 0.f;
        if (tid < 128) {
            size_t gxoff = ((size_t)(gb * TT + t)) * (4 * DOUT) + gd;
            gx0 = Gx[gxoff];
            gx1 = Gx[gxoff + DOUT];
            gx2 = Gx[gxoff + 2 * DOUT];
            gx3 = Gx[gxoff + 3 * DOUT];
        }

        if (t > 0) {
            // coalesced lane-parallel poll of this head's 64 producer flags
            const int* fl = flags + (((t - 1) * 4 + head) << 6);
            for (;;) {
                int v = __hip_atomic_load(fl + lane, __ATOMIC_RELAXED,
                                          __HIP_MEMORY_SCOPE_AGENT);
                if (__all(v != 0)) break;
                __builtin_amdgcn_s_sleep(1);
            }

            // load h fragments (B-operand layout) as u64 atomic loads
            const u64_t* hb = (const u64_t*)hfr
                + ((((size_t)(t - 1) * 4 + head) * 32) * 256 + bb * 32 + kseg * 8) / 2;
            bf16x8 hf[8];
            #pragma unroll
            for (int j = 0; j < 8; ++j) {
                const u64_t* p = hb + (size_t)(w * 8 + j) * 128;
                union { ushort_t u[8]; bf16x8 v; } fr;
                #pragma unroll
                for (int e2 = 0; e2 < 4; ++e2) {
                    u64_t q = __hip_atomic_load(p + e2, __ATOMIC_RELAXED,
                                                __HIP_MEMORY_SCOPE_AGENT);
                    unsigned q0 = (unsigned)q, q1 = (unsigned)(q >> 32);
                    fr.u[e2 * 2]     = part ? (ushort_t)(q0 >> 16) : (ushort_t)(q0 & 0xffffu);
                    fr.u[e2 * 2 + 1] = part ? (ushort_t)(q1 >> 16) : (ushort_t)(q1 & 0xffffu);
                }
                hf[j] = fr.v;
            }

            f32x4 acc[4];
            #pragma unroll
            for (int g = 0; g < 4; ++g) acc[g] = (f32x4){0.f, 0.f, 0.f, 0.f};
            #pragma unroll
            for (int g = 0; g < 4; ++g)
                #pragma unroll
                for (int j = 0; j < 8; ++j) {
                    bf16x8 a = *(const bf16x8*)&Rl[g][w * 8 + j][lane * 8];
                    acc[g] = __builtin_amdgcn_mfma_f32_16x16x32_bf16(a, hf[j], acc[g], 0, 0, 0);
                }
            // fold hi+lo halves (partner column = col^8 -> lane^8)
            #pragma unroll
            for (int g = 0; g < 4; ++g)
                #pragma unroll
                for (int r = 0; r < 4; ++r)
                    acc[g][r] += __shfl_xor(acc[g][r], 8, 64);
            // D layout: col = lane&15, row = kseg*4 + r
            if (part == 0) {
                int orow0 = kseg * 4;
                #pragma unroll
                for (int g = 0; g < 4; ++g)
                    #pragma unroll
                    for (int r = 0; r < 4; ++r)
                        gh_p[w][g][orow0 + r][bb] = acc[g][r];
            }
        } else {
            for (int i = tid; i < 4 * 4 * 16 * 8; i += 256)
                ((float*)gh_p)[i] = 0.f;
        }
        __syncthreads();

        if (tid < 128) {
            float ip = gx0 +
                gh_p[0][0][gol][gb] + gh_p[1][0][gol][gb] + gh_p[2][0][gol][gb] + gh_p[3][0][gol][gb];
            float fp = gx1 +
                gh_p[0][1][gol][gb] + gh_p[1][1][gol][gb] + gh_p[2][1][gol][gb] + gh_p[3][1][gol][gb];
            float zp = gx2 +
                gh_p[0][2][gol][gb] + gh_p[1][2][gol][gb] + gh_p[2][2][gol][gb] + gh_p[3][2][gol][gb];
            float op = gx3 +
                gh_p[0][3][gol][gb] + gh_p[1][3][gol][gb] + gh_p[2][3][gol][gb] + gh_p[3][3][gol][gb];
            float mn = fmaxf(fp + m_r, ip);
            float iv = __expf(ip - mn);
            float fv = __expf(fp + m_r - mn);
            float zc = fminf(fmaxf(zp, -9.f), 9.f);
            float th = 1.f - 2.f / (__expf(2.f * zc) + 1.f);
            c_r = fv * c_r + iv * th;
            n_r = fv * n_r + iv;
            float sig = 1.f / (1.f + __expf(-op));
            float hv = sig * c_r / n_r;
            m_r = mn;
            hs[((size_t)(gb * TT + t)) * DOUT + gd] = hv;
            unsigned hi = f2bf(hv);
            unsigned lo = f2bf(hv - bf2f((ushort_t)hi));
            __hip_atomic_store(&hfr[(size_t)t * 32768 + hslot],
                               hi | (lo << 16),
                               __ATOMIC_RELAXED, __HIP_MEMORY_SCOPE_AGENT);
        }
        __syncthreads();   // drains this block's stores (vmcnt) before signal
        if (tid == 0)
            __hip_atomic_store(&flags[((t * 4 + head) << 6) + oc], 1,
                               __ATOMIC_RELAXED, __HIP_MEMORY_SCOPE_AGENT);
    }
}

// ---------------------------------------------------------------------------
// conv3d 3x3x3 pad=1: one block per (b,t); x slice in LDS, weights via the
// packed [ci][27][16] table read through a uniform pointer (scalar loads).
// Branch-free taps (clamped index + select).
// ---------------------------------------------------------------------------
__global__ __launch_bounds__(256)
void conv3d_kernel(const float* __restrict__ in, const float* __restrict__ cw,
                   const float* __restrict__ bias, float* __restrict__ out, int relu) {
    __shared__ float xin[CIN][3][256];      // 48 KB
    int b = blockIdx.x >> 5, t = blockIdx.x & 31;
    int tid = threadIdx.x;

    for (int i = tid; i < CIN * 3 * 256; i += 256) {
        int hw = i & 255, r = i >> 8;
        int kt = r % 3, ci = r / 3;
        int tt = t + kt - 1;
        xin[ci][kt][hw] = ((unsigned)tt < TT)
            ? in[((size_t)(b * CIN + ci) * TT + tt) * 256 + hw] : 0.f;
    }
    __syncthreads();

    int h = tid >> 4, wx = tid & 15;
    f32x4 a0 = *(const f32x4*)&bias[0];
    f32x4 a1 = *(const f32x4*)&bias[4];
    f32x4 a2 = *(const f32x4*)&bias[8];
    f32x4 a3 = *(const f32x4*)&bias[12];

    for (int ci = 0; ci < CIN; ++ci) {
        #pragma unroll
        for (int kt = 0; kt < 3; ++kt) {
            #pragma unroll
            for (int kh = 0; kh < 3; ++kh) {
                int h2 = h + kh - 1;
                bool vh = (unsigned)h2 < HH;
                int h2c = vh ? h2 : 0;
                #pragma unroll
                for (int kw = 0; kw < 3; ++kw) {
                    int w2 = wx + kw - 1;
                    bool v = vh && ((unsigned)w2 < WW);
                    int w2c = ((unsigned)w2 < WW) ? w2 : 0;
                    float xv = xin[ci][kt][h2c * 16 + w2c];
                    xv = v ? xv : 0.f;
                    const float* wp = cw + (size_t)(ci * 27 + kt * 9 + kh * 3 + kw) * 16;
                    f32x4 w0 = *(const f32x4*)(wp);
                    f32x4 w1 = *(const f32x4*)(wp + 4);
                    f32x4 w2v = *(const f32x4*)(wp + 8);
                    f32x4 w3 = *(const f32x4*)(wp + 12);
                    a0 += xv * w0; a1 += xv * w1; a2 += xv * w2v; a3 += xv * w3;
                }
            }
        }
    }
    float accs[16];
    #pragma unroll
    for (int i = 0; i < 4; ++i) { accs[i] = a0[i]; accs[4+i] = a1[i]; accs[8+i] = a2[i]; accs[12+i] = a3[i]; }
    #pragma unroll
    for (int o = 0; o < 16; ++o) {
        float v = accs[o];
        if (relu) v = fmaxf(v, 0.f);
        out[((size_t)(b * COUT + o) * TT + t) * 256 + tid] = v;
    }
}

// ---------------------------------------------------------------------------
// instance norm over (T,H,W) per (b,c) + relu, in place. 128 blocks.
// ---------------------------------------------------------------------------
__global__ void inorm_relu_kernel(float* __restrict__ y) {
    __shared__ float s1[256], s2[256];
    float* p = y + (size_t)blockIdx.x * SPAT;
    float sum = 0.f, sq = 0.f;
    for (int i = threadIdx.x; i < SPAT; i += 256) {
        float v = p[i];
        sum += v; sq += v * v;
    }
    s1[threadIdx.x] = sum; s2[threadIdx.x] = sq;
    __syncthreads();
    for (int s = 128; s > 0; s >>= 1) {
        if (threadIdx.x < s) { s1[threadIdx.x] += s1[threadIdx.x + s]; s2[threadIdx.x] += s2[threadIdx.x + s]; }
        __syncthreads();
    }
    float mu = s1[0] / (float)SPAT;
    float var = s2[0] / (float)SPAT - mu * mu;
    float rs = rsqrtf(var + 1e-5f);
    for (int i = threadIdx.x; i < SPAT; i += 256) {
        float v = (p[i] - mu) * rs;
        p[i] = fmaxf(v, 0.f);
    }
}

// ---------------------------------------------------------------------------
// final combine
// ---------------------------------------------------------------------------
__global__ void combine_kernel(const float* __restrict__ hs,
                               const float* __restrict__ out3d,
                               const float* __restrict__ attn_w,
                               const float* __restrict__ attn_b,
                               float* __restrict__ out) {
    int idx = blockIdx.x * 256 + threadIdx.x;
    int hw = idx & 255;
    int t  = (idx >> 8) & 31;
    int b  = idx >> 13;
    const float* hrow = hs + ((size_t)(b * TT + t)) * DOUT;
    float dot = attn_b[0];
    float sv[16], ov[16];
    #pragma unroll
    for (int ch = 0; ch < 16; ++ch) {
        float s  = hrow[ch * 256 + hw];
        float o3 = out3d[(((size_t)(b * COUT + ch) * TT + t)) * 256 + hw];
        sv[ch] = s; ov[ch] = o3;
        dot += attn_w[ch] * s + attn_w[16 + ch] * o3;
    }
    float alpha = 1.f / (1.f + expf(-dot));
    #pragma unroll
    for (int ch = 0; ch < 16; ++ch) {
        out[(((size_t)(b * COUT + ch) * TT + t)) * 256 + hw] =
            alpha * ov[ch] + (1.f - alpha) * sv[ch];
    }
}

// ---------------------------------------------------------------------------
extern "C" void kernel_launch(void* const* d_in, const int* in_sizes, int n_in,
                              void* d_out, int out_size, void* d_ws, size_t ws_size,
                              hipStream_t stream) {
    const float* x      = (const float*)d_in[0];
    const float* c1_w   = (const float*)d_in[1];
    const float* c1_b   = (const float*)d_in[2];
    const float* c2_w   = (const float*)d_in[3];
    const float* c2_b   = (const float*)d_in[4];
    const float* c3_w   = (const float*)d_in[5];
    const float* c3_b   = (const float*)d_in[6];
    const float* pre_w  = (const float*)d_in[7];
    const float* pre_b  = (const float*)d_in[8];
    const float* lstm_W = (const float*)d_in[9];
    const float* lstm_b = (const float*)d_in[10];
    const float* lstm_R = (const float*)d_in[11];
    const float* attn_w = (const float*)d_in[12];
    const float* attn_b = (const float*)d_in[13];
    float* out = (float*)d_out;

    // workspace carve (all 16B aligned)
    float* wsf = (float*)d_ws;
    float* y1    = wsf;                // 1048576 f32
    float* y2    = y1 + 1048576;       // 1048576 f32
    float* out3d = y2 + 1048576;       // 1048576 f32
    float* hs    = out3d + 1048576;    // 1048576 f32
    float* Gx    = hs + 1048576;       // 4194304 f32
    float* cw1   = Gx + 4194304;       // 6912 f32
    float* cw2   = cw1 + 6912;         // 6912 f32
    float* cw3   = cw2 + 6912;         // 6912 f32
    float* pad   = cw3 + 6912;         // align to 16B boundary region
    ushort_t* xt   = (ushort_t*)(pad + 64);       // 1048576 bf16
    ushort_t* xs2b = xt + 1048576;                // 1048576 bf16
    unsigned* hfr  = (unsigned*)(xs2b + 1048576); // 1048576 u32 (4 MB)
    int*     flags = (int*)(hfr + 1048576);       // 8192 ints (32 KB)

    // zero sync flags (hfr slots are written before they are read)
    hipMemsetAsync(flags, 0, 8192 * sizeof(int), stream);

    // packs
    pack_xt_kernel<<<1024, 256, 0, stream>>>(x, xt);
    pack_cw_kernel<<<27, 256, 0, stream>>>(c1_w, cw1);
    pack_cw_kernel<<<27, 256, 0, stream>>>(c2_w, cw2);
    pack_cw_kernel<<<27, 256, 0, stream>>>(c3_w, cw3);

    // convs
    conv3d_kernel<<<256, 256, 0, stream>>>(x, cw1, c1_b, y1, 0);
    inorm_relu_kernel<<<128, 256, 0, stream>>>(y1);
    conv3d_kernel<<<256, 256, 0, stream>>>(y1, cw2, c2_b, y2, 1);
    conv3d_kernel<<<256, 256, 0, stream>>>(y2, cw3, c3_b, out3d, 1);

    // pre-projection -> xs2 (bf16); gate projection -> Gx (fp32); B read once
    mfma_gemm_kernel<true><<<DOUT / 64, 256, 0, stream>>>(xt, pre_w, pre_b, xs2b, DOUT, DIN);
    mfma_gemm_kernel<false><<<4 * DOUT / 64, 256, 0, stream>>>(xs2b, lstm_W, lstm_b, Gx, 4 * DOUT, DOUT);

    // recurrence: one persistent kernel, block-level flag sync
    lstm_persist_kernel<<<256, 256, 0, stream>>>(lstm_R, Gx, hfr, hs, flags);

    // combine
    combine_kernel<<<256, 256, 0, stream>>>(hs, out3d, attn_w, attn_b, out);
}

// Round 12
// 651.808 us; speedup vs baseline: 1.1336x; 1.0132x over previous
//
#include <hip/hip_runtime.h>
#include <hip/hip_bf16.h>
#include <cstddef>

// Problem constants
#define BB   8
#define CIN  16
#define COUT 16
#define TT   32
#define HH   16
#define WW   16
#define DIN  4096
#define DOUT 4096
#define NH   4
#define DH   1024
#define SPAT 8192            // T*H*W
#define NSEQ 256             // B*T

typedef __attribute__((ext_vector_type(8))) short  bf16x8;
typedef __attribute__((ext_vector_type(4))) float  f32x4;
typedef __attribute__((ext_vector_type(4))) unsigned short us4;
typedef unsigned short ushort_t;
typedef unsigned long long u64_t;

static __device__ __forceinline__ ushort_t f2bf(float f) {
    union { float f; unsigned u; } v; v.f = f;
    unsigned r = (v.u + 0x7fffu + ((v.u >> 16) & 1u)) >> 16;
    return (ushort_t)r;
}
static __device__ __forceinline__ float bf2f(ushort_t u) {
    union { unsigned u; float f; } v; v.u = ((unsigned)u) << 16;
    return v.f;
}

// ---------------------------------------------------------------------------
// pack x (B,16,32,16,16) fp32 -> xt[n=b*32+t][k=c*256+hw] bf16
// ---------------------------------------------------------------------------
__global__ void pack_xt_kernel(const float* __restrict__ x, ushort_t* __restrict__ xt) {
    int idx = blockIdx.x * 256 + threadIdx.x;          // 0 .. 262143 (4 elems each)
    int n = idx >> 10, k4 = (idx & 1023) * 4;
    int b = n >> 5, t = n & 31, c = k4 >> 8, hw = k4 & 255;
    f32x4 f = *(const f32x4*)&x[(((size_t)(b * CIN + c) * TT + t)) * 256 + hw];
    us4 o;
    #pragma unroll
    for (int i = 0; i < 4; ++i) o[i] = f2bf(f[i]);
    *(us4*)&xt[(size_t)n * DIN + k4] = o;
}

// ---------------------------------------------------------------------------
// pack all 3 conv weight sets (O,CI,3,3,3) -> cw[(ci*27+k)*16+o]; grid 81
// ---------------------------------------------------------------------------
__global__ void pack_cw_kernel(const float* __restrict__ w1, const float* __restrict__ w2,
                               const float* __restrict__ w3,
                               float* __restrict__ cw1, float* __restrict__ cw2,
                               float* __restrict__ cw3) {
    int i = blockIdx.x * 256 + threadIdx.x;   // 0..20735
    int set = i / 6912, j = i - set * 6912;
    const float* w = (set == 0) ? w1 : (set == 1) ? w2 : w3;
    float* cw      = (set == 0) ? cw1 : (set == 1) ? cw2 : cw3;
    int o = j & 15, r = j >> 4;
    int k = r % 27, ci = r / 27;
    cw[j] = w[(size_t)(o * CIN + ci) * 27 + k];
}

// ---------------------------------------------------------------------------
// MFMA GEMM, single M-tile: C[256][N] = A[256][K](bf16) * B[N][K]^T(fp32) + bias
// BM=256 BN=64 BK=64, 256 threads (4 waves), double-buffered LDS. B read once.
// ---------------------------------------------------------------------------
template<bool OUT_BF16>
__global__ __launch_bounds__(256, 2)
void mfma_gemm_kernel(const ushort_t* __restrict__ A, const float* __restrict__ B,
                      const float* __restrict__ bias, void* __restrict__ C,
                      int N, int K) {
    __shared__ ushort_t Al[2][256][64];   // 64 KB
    __shared__ ushort_t Bl[2][64][64];    // 16 KB
    int tid  = threadIdx.x;
    int lane = tid & 63;
    int wv   = tid >> 6;       // 0..3 : wave owns rows [wv*64, wv*64+64)
    int n0 = blockIdx.x * 64;

    f32x4 acc[4][4];
    #pragma unroll
    for (int i = 0; i < 4; ++i)
        #pragma unroll
        for (int j = 0; j < 4; ++j) acc[i][j] = (f32x4){0.f, 0.f, 0.f, 0.f};

    auto stageA = [&](int buf, int k0) {
        #pragma unroll
        for (int q = 0; q < 8; ++q) {
            int row = wv * 64 + q * 8 + (lane >> 3);
            const ushort_t* g = A + (size_t)row * K + k0 + (lane & 7) * 8;
            __builtin_amdgcn_global_load_lds(
                (const __attribute__((address_space(1))) void*)g,
                (__attribute__((address_space(3))) void*)&Al[buf][wv * 64 + q * 8][0],
                16, 0, 0);
        }
    };
    auto stageB = [&](int buf, int k0) {
        int r = tid >> 2;               // 0..63
        int cs = (tid & 3) * 16;        // 0,16,32,48
        const float* g = B + (size_t)(n0 + r) * K + k0 + cs;
        f32x4 f0 = *(const f32x4*)(g);
        f32x4 f1 = *(const f32x4*)(g + 4);
        f32x4 f2 = *(const f32x4*)(g + 8);
        f32x4 f3 = *(const f32x4*)(g + 12);
        union { ushort_t u[16]; bf16x8 v[2]; } pk;
        #pragma unroll
        for (int i = 0; i < 4; ++i) {
            pk.u[i]      = f2bf(f0[i]);
            pk.u[4 + i]  = f2bf(f1[i]);
            pk.u[8 + i]  = f2bf(f2[i]);
            pk.u[12 + i] = f2bf(f3[i]);
        }
        *(bf16x8*)&Bl[buf][r][cs]     = pk.v[0];
        *(bf16x8*)&Bl[buf][r][cs + 8] = pk.v[1];
    };
    auto compute = [&](int buf) {
        #pragma unroll
        for (int ks = 0; ks < 2; ++ks) {
            bf16x8 af[4], bfr[4];
            #pragma unroll
            for (int i = 0; i < 4; ++i)
                af[i] = *(const bf16x8*)&Al[buf][wv * 64 + i * 16 + (lane & 15)][ks * 32 + (lane >> 4) * 8];
            #pragma unroll
            for (int j = 0; j < 4; ++j)
                bfr[j] = *(const bf16x8*)&Bl[buf][j * 16 + (lane & 15)][ks * 32 + (lane >> 4) * 8];
            #pragma unroll
            for (int i = 0; i < 4; ++i)
                #pragma unroll
                for (int j = 0; j < 4; ++j)
                    acc[i][j] = __builtin_amdgcn_mfma_f32_16x16x32_bf16(af[i], bfr[j], acc[i][j], 0, 0, 0);
        }
    };

    stageA(0, 0); stageB(0, 0);
    __syncthreads();
    int nk = K / 64;
    int cur = 0;
    for (int t = 0; t < nk; ++t) {
        if (t + 1 < nk) { stageA(cur ^ 1, (t + 1) * 64); stageB(cur ^ 1, (t + 1) * 64); }
        compute(cur);
        __syncthreads();
        cur ^= 1;
    }

    #pragma unroll
    for (int i = 0; i < 4; ++i) {
        int row = wv * 64 + i * 16 + (lane >> 4) * 4;
        #pragma unroll
        for (int j = 0; j < 4; ++j) {
            int col = n0 + j * 16 + (lane & 15);
            float bv = bias[col];
            #pragma unroll
            for (int r = 0; r < 4; ++r) {
                float v = acc[i][j][r] + bv;
                if constexpr (OUT_BF16) ((ushort_t*)C)[(size_t)(row + r) * N + col] = f2bf(v);
                else                    ((float*)C)[(size_t)(row + r) * N + col] = v;
            }
        }
    }
}

// ---------------------------------------------------------------------------
// Persistent sLSTM (R11 sync, hs store removed):
//  - R (fp32) staged directly into LDS in MFMA fragment order, once.
//  - h via hfr u32 slots [t][head][ks][b][k'] = (lo<<16|hi) bf16 pair; relaxed
//    agent atomics (LLC-coherent, no cache-wide fences).
//  - flags[t][head][oc]: tid0 stores after __syncthreads (vmcnt drained);
//    consumers poll the 64 flags of their head with one coalesced lane-load.
// grid: 256 blocks = head(4) x ochunk(64 of 16 o's), 256 threads, 1 block/CU.
// ---------------------------------------------------------------------------
__global__ __launch_bounds__(256, 1)
void lstm_persist_kernel(const float* __restrict__ R,       // [4][4][1024][1024] fp32
                         const float* __restrict__ Gx,      // [256][16384]
                         unsigned* __restrict__ hfr,        // [32][4][32][8][32] u32
                         int* __restrict__ flags) {         // [32][4][64], zeroed
    __shared__ ushort_t Rl[4][32][64 * 8];   // [gate][ks][lane*8] = 128 KB
    __shared__ float gh_p[4][4][16][8];      // [wave][gate][o_l][b] = 8 KB

    int tid  = threadIdx.x;
    int lane = tid & 63;
    int w    = tid >> 6;               // wave = K-chunk (ks in [w*8, w*8+8))
    int head = blockIdx.x >> 6;
    int oc   = blockIdx.x & 63;

    // ---- stage R slice fp32 -> bf16 LDS in fragment order, once ----
    #pragma unroll 4
    for (int n = 0; n < 64; ++n) {
        int g = n >> 4, r = n & 15;
        const float* src = R + ((size_t)((head * 4 + g) * DH + oc * 16 + r)) * DH + tid * 4;
        f32x4 f = *(const f32x4*)src;
        int k0 = tid * 4;
        int ks = k0 >> 5;
        int kI = (k0 >> 3) & 3;
        int e8 = k0 & 7;               // 0 or 4
        union { ushort_t u[4]; u64_t q; } pk;
        #pragma unroll
        for (int e = 0; e < 4; ++e) pk.u[e] = f2bf(f[e]);
        *(u64_t*)&Rl[g][ks][((kI << 4) | r) * 8 + e8] = pk.q;
    }

    int arow = lane & 15;          // packed-B column (part,bb); also D column
    int part = arow >> 3;          // 0: hi half of h, 1: lo half
    int bb   = arow & 7;           // batch
    int kseg = lane >> 4;          // 0..3

    // gate-phase identity (tid < 128)
    int gb  = tid >> 4;            // batch
    int gol = tid & 15;            // o_local
    int gd  = head * DH + oc * 16 + gol;
    int o_h = oc * 16 + gol;       // o within head (= k index for next step)
    unsigned hslot = ((unsigned)head * 32 + (o_h >> 5)) * 256 + gb * 32 + (o_h & 31);
    float c_r = 0.f, n_r = 0.f, m_r = 0.f;

    __syncthreads();

    for (int t = 0; t < TT; ++t) {
        // prefetch this step's Gx (h-independent) before the flag wait
        float gx0 = 0.f, gx1 = 0.f, gx2 = 0.f, gx3 = 0.f;
        if (tid < 128) {
            size_t gxoff = ((size_t)(gb * TT + t)) * (4 * DOUT) + gd;
            gx0 = Gx[gxoff];
            gx1 = Gx[gxoff + DOUT];
            gx2 = Gx[gxoff + 2 * DOUT];
            gx3 = Gx[gxoff + 3 * DOUT];
        }

        if (t > 0) {
            // coalesced lane-parallel poll of this head's 64 producer flags
            const int* fl = flags + (((t - 1) * 4 + head) << 6);
            for (;;) {
                int v = __hip_atomic_load(fl + lane, __ATOMIC_RELAXED,
                                          __HIP_MEMORY_SCOPE_AGENT);
                if (__all(v != 0)) break;
                __builtin_amdgcn_s_sleep(1);
            }

            // load h fragments (B-operand layout) as u64 atomic loads
            const u64_t* hb = (const u64_t*)hfr
                + ((((size_t)(t - 1) * 4 + head) * 32) * 256 + bb * 32 + kseg * 8) / 2;
            bf16x8 hf[8];
            #pragma unroll
            for (int j = 0; j < 8; ++j) {
                const u64_t* p = hb + (size_t)(w * 8 + j) * 128;
                union { ushort_t u[8]; bf16x8 v; } fr;
                #pragma unroll
                for (int e2 = 0; e2 < 4; ++e2) {
                    u64_t q = __hip_atomic_load(p + e2, __ATOMIC_RELAXED,
                                                __HIP_MEMORY_SCOPE_AGENT);
                    unsigned q0 = (unsigned)q, q1 = (unsigned)(q >> 32);
                    fr.u[e2 * 2]     = part ? (ushort_t)(q0 >> 16) : (ushort_t)(q0 & 0xffffu);
                    fr.u[e2 * 2 + 1] = part ? (ushort_t)(q1 >> 16) : (ushort_t)(q1 & 0xffffu);
                }
                hf[j] = fr.v;
            }

            f32x4 acc[4];
            #pragma unroll
            for (int g = 0; g < 4; ++g) acc[g] = (f32x4){0.f, 0.f, 0.f, 0.f};
            #pragma unroll
            for (int g = 0; g < 4; ++g)
                #pragma unroll
                for (int j = 0; j < 8; ++j) {
                    bf16x8 a = *(const bf16x8*)&Rl[g][w * 8 + j][lane * 8];
                    acc[g] = __builtin_amdgcn_mfma_f32_16x16x32_bf16(a, hf[j], acc[g], 0, 0, 0);
                }
            // fold hi+lo halves (partner column = col^8 -> lane^8)
            #pragma unroll
            for (int g = 0; g < 4; ++g)
                #pragma unroll
                for (int r = 0; r < 4; ++r)
                    acc[g][r] += __shfl_xor(acc[g][r], 8, 64);
            // D layout: col = lane&15, row = kseg*4 + r
            if (part == 0) {
                int orow0 = kseg * 4;
                #pragma unroll
                for (int g = 0; g < 4; ++g)
                    #pragma unroll
                    for (int r = 0; r < 4; ++r)
                        gh_p[w][g][orow0 + r][bb] = acc[g][r];
            }
        } else {
            for (int i = tid; i < 4 * 4 * 16 * 8; i += 256)
                ((float*)gh_p)[i] = 0.f;
        }
        __syncthreads();

        if (tid < 128) {
            float ip = gx0 +
                gh_p[0][0][gol][gb] + gh_p[1][0][gol][gb] + gh_p[2][0][gol][gb] + gh_p[3][0][gol][gb];
            float fp = gx1 +
                gh_p[0][1][gol][gb] + gh_p[1][1][gol][gb] + gh_p[2][1][gol][gb] + gh_p[3][1][gol][gb];
            float zp = gx2 +
                gh_p[0][2][gol][gb] + gh_p[1][2][gol][gb] + gh_p[2][2][gol][gb] + gh_p[3][2][gol][gb];
            float op = gx3 +
                gh_p[0][3][gol][gb] + gh_p[1][3][gol][gb] + gh_p[2][3][gol][gb] + gh_p[3][3][gol][gb];
            float mn = fmaxf(fp + m_r, ip);
            float iv = __expf(ip - mn);
            float fv = __expf(fp + m_r - mn);
            float zc = fminf(fmaxf(zp, -9.f), 9.f);
            float th = 1.f - 2.f / (__expf(2.f * zc) + 1.f);
            c_r = fv * c_r + iv * th;
            n_r = fv * n_r + iv;
            float sig = 1.f / (1.f + __expf(-op));
            float hv = sig * c_r / n_r;
            m_r = mn;
            unsigned hi = f2bf(hv);
            unsigned lo = f2bf(hv - bf2f((ushort_t)hi));
            __hip_atomic_store(&hfr[(size_t)t * 32768 + hslot],
                               hi | (lo << 16),
                               __ATOMIC_RELAXED, __HIP_MEMORY_SCOPE_AGENT);
        }
        __syncthreads();   // drains this block's stores (vmcnt) before signal
        if (tid == 0)
            __hip_atomic_store(&flags[((t * 4 + head) << 6) + oc], 1,
                               __ATOMIC_RELAXED, __HIP_MEMORY_SCOPE_AGENT);
    }
}

// ---------------------------------------------------------------------------
// conv3d 3x3x3 pad=1, split-o: 512 blocks = (b,t,half); each block computes 8
// output channels. x slice in LDS (optionally instance-norm+relu applied
// inline); weights from packed [ci][27][16] table via uniform scalar loads.
// ---------------------------------------------------------------------------
template<bool NORM>
__global__ __launch_bounds__(256)
void conv3d_kernel(const float* __restrict__ in, const float* __restrict__ cw,
                   const float* __restrict__ bias, const float* __restrict__ stats,
                   float* __restrict__ out, int relu) {
    __shared__ float xin[CIN][3][256];      // 48 KB
    int blk = blockIdx.x;
    int b = blk >> 6, t = (blk >> 1) & 31, half = blk & 1;
    int tid = threadIdx.x;

    for (int i = tid; i < CIN * 3 * 256; i += 256) {
        int hw = i & 255, r = i >> 8;
        int kt = r % 3, ci = r / 3;
        int tt = t + kt - 1;
        float v = 0.f;
        if ((unsigned)tt < TT) {
            v = in[((size_t)(b * CIN + ci) * TT + tt) * 256 + hw];
            if constexpr (NORM) {
                float mu = stats[(b * CIN + ci) * 2];
                float rs = stats[(b * CIN + ci) * 2 + 1];
                v = fmaxf((v - mu) * rs, 0.f);
            }
        }
        xin[ci][kt][hw] = v;
    }
    __syncthreads();

    int h = tid >> 4, wx = tid & 15;
    f32x4 a0 = *(const f32x4*)&bias[half * 8];
    f32x4 a1 = *(const f32x4*)&bias[half * 8 + 4];

    for (int ci = 0; ci < CIN; ++ci) {
        #pragma unroll
        for (int kt = 0; kt < 3; ++kt) {
            #pragma unroll
            for (int kh = 0; kh < 3; ++kh) {
                int h2 = h + kh - 1;
                bool vh = (unsigned)h2 < HH;
                int h2c = vh ? h2 : 0;
                #pragma unroll
                for (int kw = 0; kw < 3; ++kw) {
                    int w2 = wx + kw - 1;
                    bool v = vh && ((unsigned)w2 < WW);
                    int w2c = ((unsigned)w2 < WW) ? w2 : 0;
                    float xv = xin[ci][kt][h2c * 16 + w2c];
                    xv = v ? xv : 0.f;
                    const float* wp = cw + (size_t)(ci * 27 + kt * 9 + kh * 3 + kw) * 16 + half * 8;
                    f32x4 w0 = *(const f32x4*)(wp);
                    f32x4 w1 = *(const f32x4*)(wp + 4);
                    a0 += xv * w0; a1 += xv * w1;
                }
            }
        }
    }
    float accs[8];
    #pragma unroll
    for (int i = 0; i < 4; ++i) { accs[i] = a0[i]; accs[4 + i] = a1[i]; }
    #pragma unroll
    for (int o = 0; o < 8; ++o) {
        float v = accs[o];
        if (relu) v = fmaxf(v, 0.f);
        out[((size_t)(b * COUT + half * 8 + o) * TT + t) * 256 + tid] = v;
    }
}

// ---------------------------------------------------------------------------
// instance-norm stats per (b,c): stats[bc] = {mu, rsqrt(var+eps)}. 128 blocks.
// ---------------------------------------------------------------------------
__global__ void inorm_stats_kernel(const float* __restrict__ y, float* __restrict__ stats) {
    __shared__ float s1[256], s2[256];
    const float* p = y + (size_t)blockIdx.x * SPAT;
    float sum = 0.f, sq = 0.f;
    for (int i = threadIdx.x; i < SPAT; i += 256) {
        float v = p[i];
        sum += v; sq += v * v;
    }
    s1[threadIdx.x] = sum; s2[threadIdx.x] = sq;
    __syncthreads();
    for (int s = 128; s > 0; s >>= 1) {
        if (threadIdx.x < s) { s1[threadIdx.x] += s1[threadIdx.x + s]; s2[threadIdx.x] += s2[threadIdx.x + s]; }
        __syncthreads();
    }
    if (threadIdx.x == 0) {
        float mu = s1[0] / (float)SPAT;
        float var = s2[0] / (float)SPAT - mu * mu;
        stats[blockIdx.x * 2]     = mu;
        stats[blockIdx.x * 2 + 1] = rsqrtf(var + 1e-5f);
    }
}

// ---------------------------------------------------------------------------
// final combine: h reconstructed from the u32 slots (bf2f(hi)+bf2f(lo))
// ---------------------------------------------------------------------------
__global__ void combine_kernel(const unsigned* __restrict__ hfr,
                               const float* __restrict__ out3d,
                               const float* __restrict__ attn_w,
                               const float* __restrict__ attn_b,
                               float* __restrict__ out) {
    int idx = blockIdx.x * 256 + threadIdx.x;
    int hw = idx & 255;
    int t  = (idx >> 8) & 31;
    int b  = idx >> 13;
    float dot = attn_b[0];
    float sv[16], ov[16];
    #pragma unroll
    for (int ch = 0; ch < 16; ++ch) {
        int d = ch * 256 + hw;
        int head = d >> 10, o_h = d & 1023;
        size_t slot = (size_t)t * 32768 + (size_t)head * 8192
                    + (o_h >> 5) * 256 + b * 32 + (o_h & 31);
        unsigned v32 = hfr[slot];
        float s = bf2f((ushort_t)(v32 & 0xffffu)) + bf2f((ushort_t)(v32 >> 16));
        float o3 = out3d[(((size_t)(b * COUT + ch) * TT + t)) * 256 + hw];
        sv[ch] = s; ov[ch] = o3;
        dot += attn_w[ch] * s + attn_w[16 + ch] * o3;
    }
    float alpha = 1.f / (1.f + expf(-dot));
    #pragma unroll
    for (int ch = 0; ch < 16; ++ch) {
        out[(((size_t)(b * COUT + ch) * TT + t)) * 256 + hw] =
            alpha * ov[ch] + (1.f - alpha) * sv[ch];
    }
}

// ---------------------------------------------------------------------------
extern "C" void kernel_launch(void* const* d_in, const int* in_sizes, int n_in,
                              void* d_out, int out_size, void* d_ws, size_t ws_size,
                              hipStream_t stream) {
    const float* x      = (const float*)d_in[0];
    const float* c1_w   = (const float*)d_in[1];
    const float* c1_b   = (const float*)d_in[2];
    const float* c2_w   = (const float*)d_in[3];
    const float* c2_b   = (const float*)d_in[4];
    const float* c3_w   = (const float*)d_in[5];
    const float* c3_b   = (const float*)d_in[6];
    const float* pre_w  = (const float*)d_in[7];
    const float* pre_b  = (const float*)d_in[8];
    const float* lstm_W = (const float*)d_in[9];
    const float* lstm_b = (const float*)d_in[10];
    const float* lstm_R = (const float*)d_in[11];
    const float* attn_w = (const float*)d_in[12];
    const float* attn_b = (const float*)d_in[13];
    float* out = (float*)d_out;

    // workspace carve (all 16B aligned)
    float* wsf = (float*)d_ws;
    float* y1    = wsf;                // 1048576 f32
    float* y2    = y1 + 1048576;       // 1048576 f32
    float* out3d = y2 + 1048576;       // 1048576 f32
    float* Gx    = out3d + 1048576;    // 4194304 f32
    float* cw1   = Gx + 4194304;       // 6912 f32
    float* cw2   = cw1 + 6912;         // 6912 f32
    float* cw3   = cw2 + 6912;         // 6912 f32
    float* stats = cw3 + 6912;         // 256 f32
    float* pad   = stats + 256;
    ushort_t* xt   = (ushort_t*)(pad + 64);       // 1048576 bf16
    ushort_t* xs2b = xt + 1048576;                // 1048576 bf16
    unsigned* hfr  = (unsigned*)(xs2b + 1048576); // 1048576 u32 (4 MB)
    int*     flags = (int*)(hfr + 1048576);       // 8192 ints (32 KB)

    // zero sync flags (hfr slots are written before they are read)
    hipMemsetAsync(flags, 0, 8192 * sizeof(int), stream);

    // packs
    pack_xt_kernel<<<1024, 256, 0, stream>>>(x, xt);
    pack_cw_kernel<<<81, 256, 0, stream>>>(c1_w, c2_w, c3_w, cw1, cw2, cw3);

    // convs (split-o: 512 blocks each); inorm folded into conv2 staging
    conv3d_kernel<false><<<512, 256, 0, stream>>>(x, cw1, c1_b, nullptr, y1, 0);
    inorm_stats_kernel<<<128, 256, 0, stream>>>(y1, stats);
    conv3d_kernel<true><<<512, 256, 0, stream>>>(y1, cw2, c2_b, stats, y2, 1);
    conv3d_kernel<false><<<512, 256, 0, stream>>>(y2, cw3, c3_b, nullptr, out3d, 1);

    // pre-projection -> xs2 (bf16); gate projection -> Gx (fp32); B read once
    mfma_gemm_kernel<true><<<DOUT / 64, 256, 0, stream>>>(xt, pre_w, pre_b, xs2b, DOUT, DIN);
    mfma_gemm_kernel<false><<<4 * DOUT / 64, 256, 0, stream>>>(xs2b, lstm_W, lstm_b, Gx, 4 * DOUT, DOUT);

    // recurrence: one persistent kernel, block-level flag sync
    lstm_persist_kernel<<<256, 256, 0, stream>>>(lstm_R, Gx, hfr, flags);

    // combine (reads h from slots)
    combine_kernel<<<256, 256, 0, stream>>>(hfr, out3d, attn_w, attn_b, out);
}

// Round 13
// 590.156 us; speedup vs baseline: 1.2520x; 1.1045x over previous
//
#include <hip/hip_runtime.h>
#include <hip/hip_bf16.h>
#include <cstddef>

// Problem constants
#define BB   8
#define CIN  16
#define COUT 16
#define TT   32
#define HH   16
#define WW   16
#define DIN  4096
#define DOUT 4096
#define NH   4
#define DH   1024
#define SPAT 8192            // T*H*W
#define NSEQ 256             // B*T

typedef __attribute__((ext_vector_type(8))) short  bf16x8;
typedef __attribute__((ext_vector_type(4))) float  f32x4;
typedef __attribute__((ext_vector_type(4))) unsigned short us4;
typedef unsigned short ushort_t;
typedef unsigned long long u64_t;

static __device__ __forceinline__ ushort_t f2bf(float f) {
    union { float f; unsigned u; } v; v.f = f;
    unsigned r = (v.u + 0x7fffu + ((v.u >> 16) & 1u)) >> 16;
    return (ushort_t)r;
}
static __device__ __forceinline__ float bf2f(ushort_t u) {
    union { unsigned u; float f; } v; v.u = ((unsigned)u) << 16;
    return v.f;
}

// ---------------------------------------------------------------------------
// pack x (B,16,32,16,16) fp32 -> xt[n=b*32+t][k=c*256+hw] bf16
// ---------------------------------------------------------------------------
__global__ void pack_xt_kernel(const float* __restrict__ x, ushort_t* __restrict__ xt) {
    int idx = blockIdx.x * 256 + threadIdx.x;          // 0 .. 262143 (4 elems each)
    int n = idx >> 10, k4 = (idx & 1023) * 4;
    int b = n >> 5, t = n & 31, c = k4 >> 8, hw = k4 & 255;
    f32x4 f = *(const f32x4*)&x[(((size_t)(b * CIN + c) * TT + t)) * 256 + hw];
    us4 o;
    #pragma unroll
    for (int i = 0; i < 4; ++i) o[i] = f2bf(f[i]);
    *(us4*)&xt[(size_t)n * DIN + k4] = o;
}

// ---------------------------------------------------------------------------
// pack all 3 conv weight sets (O,CI,3,3,3) -> cw[(ci*27+k)*16+o]; grid 81
// ---------------------------------------------------------------------------
__global__ void pack_cw_kernel(const float* __restrict__ w1, const float* __restrict__ w2,
                               const float* __restrict__ w3,
                               float* __restrict__ cw1, float* __restrict__ cw2,
                               float* __restrict__ cw3) {
    int i = blockIdx.x * 256 + threadIdx.x;   // 0..20735
    int set = i / 6912, j = i - set * 6912;
    const float* w = (set == 0) ? w1 : (set == 1) ? w2 : w3;
    float* cw      = (set == 0) ? cw1 : (set == 1) ? cw2 : cw3;
    int o = j & 15, r = j >> 4;
    int k = r % 27, ci = r / 27;
    cw[j] = w[(size_t)(o * CIN + ci) * 27 + k];
}

// ---------------------------------------------------------------------------
// MFMA GEMM, single M-tile: C[256][N] = A[256][K](bf16) * B[N][K]^T(fp32) + bias
// BM=256, BN template (16/32/64), BK=64; 256 threads (4 waves), dbuf LDS.
// Each N-column owned by exactly one block -> B read exactly once from HBM.
// grid N/BN blocks.
// ---------------------------------------------------------------------------
template<int BN, bool OUT_BF16>
__global__ __launch_bounds__(256, 2)
void mfma_gemm_kernel(const ushort_t* __restrict__ A, const float* __restrict__ B,
                      const float* __restrict__ bias, void* __restrict__ C,
                      int N, int K) {
    constexpr int NF  = BN / 16;          // N fragments per wave
    constexpr int TPR = 256 / BN;         // threads per B row
    constexpr int FPT = 64 / TPR;         // floats per thread per stageB
    __shared__ ushort_t Al[2][256][64];   // 64 KB
    __shared__ ushort_t Bl[2][BN][64];
    int tid  = threadIdx.x;
    int lane = tid & 63;
    int wv   = tid >> 6;       // 0..3 : wave owns rows [wv*64, wv*64+64)
    int n0 = blockIdx.x * BN;

    f32x4 acc[4][NF];
    #pragma unroll
    for (int i = 0; i < 4; ++i)
        #pragma unroll
        for (int j = 0; j < NF; ++j) acc[i][j] = (f32x4){0.f, 0.f, 0.f, 0.f};

    auto stageA = [&](int buf, int k0) {
        #pragma unroll
        for (int q = 0; q < 8; ++q) {
            int row = wv * 64 + q * 8 + (lane >> 3);
            const ushort_t* g = A + (size_t)row * K + k0 + (lane & 7) * 8;
            __builtin_amdgcn_global_load_lds(
                (const __attribute__((address_space(1))) void*)g,
                (__attribute__((address_space(3))) void*)&Al[buf][wv * 64 + q * 8][0],
                16, 0, 0);
        }
    };
    auto stageB = [&](int buf, int k0) {
        int r  = tid / TPR;               // 0..BN-1
        int cs = (tid % TPR) * FPT;       // start col
        const float* g = B + (size_t)(n0 + r) * K + k0 + cs;
        #pragma unroll
        for (int q = 0; q < FPT / 4; ++q) {
            f32x4 f = *(const f32x4*)(g + q * 4);
            us4 pk;
            #pragma unroll
            for (int e = 0; e < 4; ++e) pk[e] = f2bf(f[e]);
            *(us4*)&Bl[buf][r][cs + q * 4] = pk;
        }
    };
    auto compute = [&](int buf) {
        #pragma unroll
        for (int ks = 0; ks < 2; ++ks) {
            bf16x8 af[4], bfr[NF];
            #pragma unroll
            for (int i = 0; i < 4; ++i)
                af[i] = *(const bf16x8*)&Al[buf][wv * 64 + i * 16 + (lane & 15)][ks * 32 + (lane >> 4) * 8];
            #pragma unroll
            for (int j = 0; j < NF; ++j)
                bfr[j] = *(const bf16x8*)&Bl[buf][j * 16 + (lane & 15)][ks * 32 + (lane >> 4) * 8];
            #pragma unroll
            for (int i = 0; i < 4; ++i)
                #pragma unroll
                for (int j = 0; j < NF; ++j)
                    acc[i][j] = __builtin_amdgcn_mfma_f32_16x16x32_bf16(af[i], bfr[j], acc[i][j], 0, 0, 0);
        }
    };

    stageA(0, 0); stageB(0, 0);
    __syncthreads();
    int nk = K / 64;
    int cur = 0;
    for (int t = 0; t < nk; ++t) {
        if (t + 1 < nk) { stageA(cur ^ 1, (t + 1) * 64); stageB(cur ^ 1, (t + 1) * 64); }
        compute(cur);
        __syncthreads();
        cur ^= 1;
    }

    #pragma unroll
    for (int i = 0; i < 4; ++i) {
        int row = wv * 64 + i * 16 + (lane >> 4) * 4;
        #pragma unroll
        for (int j = 0; j < NF; ++j) {
            int col = n0 + j * 16 + (lane & 15);
            float bv = bias[col];
            #pragma unroll
            for (int r = 0; r < 4; ++r) {
                float v = acc[i][j][r] + bv;
                if constexpr (OUT_BF16) ((ushort_t*)C)[(size_t)(row + r) * N + col] = f2bf(v);
                else                    ((float*)C)[(size_t)(row + r) * N + col] = v;
            }
        }
    }
}

// ---------------------------------------------------------------------------
// Persistent sLSTM (best-known sync):
//  - R (fp32) staged directly into LDS in MFMA fragment order, once.
//  - h via hfr u32 slots [t][head][ks][b][k'] = (lo<<16|hi) bf16 pair; relaxed
//    agent atomics (LLC-coherent, no cache-wide fences).
//  - flags[t][head][oc]: tid0 stores after __syncthreads (vmcnt drained);
//    consumers poll the 64 flags of their head with one coalesced lane-load.
// grid: 256 blocks = head(4) x ochunk(64 of 16 o's), 256 threads, 1 block/CU.
// ---------------------------------------------------------------------------
__global__ __launch_bounds__(256, 1)
void lstm_persist_kernel(const float* __restrict__ R,       // [4][4][1024][1024] fp32
                         const float* __restrict__ Gx,      // [256][16384]
                         unsigned* __restrict__ hfr,        // [32][4][32][8][32] u32
                         int* __restrict__ flags) {         // [32][4][64], zeroed
    __shared__ ushort_t Rl[4][32][64 * 8];   // [gate][ks][lane*8] = 128 KB
    __shared__ float gh_p[4][4][16][8];      // [wave][gate][o_l][b] = 8 KB

    int tid  = threadIdx.x;
    int lane = tid & 63;
    int w    = tid >> 6;               // wave = K-chunk (ks in [w*8, w*8+8))
    int head = blockIdx.x >> 6;
    int oc   = blockIdx.x & 63;

    // ---- stage R slice fp32 -> bf16 LDS in fragment order, once ----
    #pragma unroll 4
    for (int n = 0; n < 64; ++n) {
        int g = n >> 4, r = n & 15;
        const float* src = R + ((size_t)((head * 4 + g) * DH + oc * 16 + r)) * DH + tid * 4;
        f32x4 f = *(const f32x4*)src;
        int k0 = tid * 4;
        int ks = k0 >> 5;
        int kI = (k0 >> 3) & 3;
        int e8 = k0 & 7;               // 0 or 4
        union { ushort_t u[4]; u64_t q; } pk;
        #pragma unroll
        for (int e = 0; e < 4; ++e) pk.u[e] = f2bf(f[e]);
        *(u64_t*)&Rl[g][ks][((kI << 4) | r) * 8 + e8] = pk.q;
    }

    int arow = lane & 15;          // packed-B column (part,bb); also D column
    int part = arow >> 3;          // 0: hi half of h, 1: lo half
    int bb   = arow & 7;           // batch
    int kseg = lane >> 4;          // 0..3

    // gate-phase identity (tid < 128)
    int gb  = tid >> 4;            // batch
    int gol = tid & 15;            // o_local
    int gd  = head * DH + oc * 16 + gol;
    int o_h = oc * 16 + gol;       // o within head (= k index for next step)
    unsigned hslot = ((unsigned)head * 32 + (o_h >> 5)) * 256 + gb * 32 + (o_h & 31);
    float c_r = 0.f, n_r = 0.f, m_r = 0.f;

    __syncthreads();

    for (int t = 0; t < TT; ++t) {
        // prefetch this step's Gx (h-independent) before the flag wait
        float gx0 = 0.f, gx1 = 0.f, gx2 = 0.f, gx3 = 0.f;
        if (tid < 128) {
            size_t gxoff = ((size_t)(gb * TT + t)) * (4 * DOUT) + gd;
            gx0 = Gx[gxoff];
            gx1 = Gx[gxoff + DOUT];
            gx2 = Gx[gxoff + 2 * DOUT];
            gx3 = Gx[gxoff + 3 * DOUT];
        }

        if (t > 0) {
            // coalesced lane-parallel poll of this head's 64 producer flags
            const int* fl = flags + (((t - 1) * 4 + head) << 6);
            for (;;) {
                int v = __hip_atomic_load(fl + lane, __ATOMIC_RELAXED,
                                          __HIP_MEMORY_SCOPE_AGENT);
                if (__all(v != 0)) break;
                __builtin_amdgcn_s_sleep(1);
            }

            // load h fragments (B-operand layout) as u64 atomic loads
            const u64_t* hb = (const u64_t*)hfr
                + ((((size_t)(t - 1) * 4 + head) * 32) * 256 + bb * 32 + kseg * 8) / 2;
            bf16x8 hf[8];
            #pragma unroll
            for (int j = 0; j < 8; ++j) {
                const u64_t* p = hb + (size_t)(w * 8 + j) * 128;
                union { ushort_t u[8]; bf16x8 v; } fr;
                #pragma unroll
                for (int e2 = 0; e2 < 4; ++e2) {
                    u64_t q = __hip_atomic_load(p + e2, __ATOMIC_RELAXED,
                                                __HIP_MEMORY_SCOPE_AGENT);
                    unsigned q0 = (unsigned)q, q1 = (unsigned)(q >> 32);
                    fr.u[e2 * 2]     = part ? (ushort_t)(q0 >> 16) : (ushort_t)(q0 & 0xffffu);
                    fr.u[e2 * 2 + 1] = part ? (ushort_t)(q1 >> 16) : (ushort_t)(q1 & 0xffffu);
                }
                hf[j] = fr.v;
            }

            f32x4 acc[4];
            #pragma unroll
            for (int g = 0; g < 4; ++g) acc[g] = (f32x4){0.f, 0.f, 0.f, 0.f};
            #pragma unroll
            for (int g = 0; g < 4; ++g)
                #pragma unroll
                for (int j = 0; j < 8; ++j) {
                    bf16x8 a = *(const bf16x8*)&Rl[g][w * 8 + j][lane * 8];
                    acc[g] = __builtin_amdgcn_mfma_f32_16x16x32_bf16(a, hf[j], acc[g], 0, 0, 0);
                }
            // fold hi+lo halves (partner column = col^8 -> lane^8)
            #pragma unroll
            for (int g = 0; g < 4; ++g)
                #pragma unroll
                for (int r = 0; r < 4; ++r)
                    acc[g][r] += __shfl_xor(acc[g][r], 8, 64);
            // D layout: col = lane&15, row = kseg*4 + r
            if (part == 0) {
                int orow0 = kseg * 4;
                #pragma unroll
                for (int g = 0; g < 4; ++g)
                    #pragma unroll
                    for (int r = 0; r < 4; ++r)
                        gh_p[w][g][orow0 + r][bb] = acc[g][r];
            }
        } else {
            for (int i = tid; i < 4 * 4 * 16 * 8; i += 256)
                ((float*)gh_p)[i] = 0.f;
        }
        __syncthreads();

        if (tid < 128) {
            float ip = gx0 +
                gh_p[0][0][gol][gb] + gh_p[1][0][gol][gb] + gh_p[2][0][gol][gb] + gh_p[3][0][gol][gb];
            float fp = gx1 +
                gh_p[0][1][gol][gb] + gh_p[1][1][gol][gb] + gh_p[2][1][gol][gb] + gh_p[3][1][gol][gb];
            float zp = gx2 +
                gh_p[0][2][gol][gb] + gh_p[1][2][gol][gb] + gh_p[2][2][gol][gb] + gh_p[3][2][gol][gb];
            float op = gx3 +
                gh_p[0][3][gol][gb] + gh_p[1][3][gol][gb] + gh_p[2][3][gol][gb] + gh_p[3][3][gol][gb];
            float mn = fmaxf(fp + m_r, ip);
            float iv = __expf(ip - mn);
            float fv = __expf(fp + m_r - mn);
            float zc = fminf(fmaxf(zp, -9.f), 9.f);
            float th = 1.f - 2.f / (__expf(2.f * zc) + 1.f);
            c_r = fv * c_r + iv * th;
            n_r = fv * n_r + iv;
            float sig = 1.f / (1.f + __expf(-op));
            float hv = sig * c_r / n_r;
            m_r = mn;
            unsigned hi = f2bf(hv);
            unsigned lo = f2bf(hv - bf2f((ushort_t)hi));
            __hip_atomic_store(&hfr[(size_t)t * 32768 + hslot],
                               hi | (lo << 16),
                               __ATOMIC_RELAXED, __HIP_MEMORY_SCOPE_AGENT);
        }
        __syncthreads();   // drains this block's stores (vmcnt) before signal
        if (tid == 0)
            __hip_atomic_store(&flags[((t * 4 + head) << 6) + oc], 1,
                               __ATOMIC_RELAXED, __HIP_MEMORY_SCOPE_AGENT);
    }
}

// ---------------------------------------------------------------------------
// conv3d 3x3x3 pad=1, split-o: 512 blocks = (b,t,half); each block computes 8
// output channels. x slice in LDS (optionally instance-norm+relu applied
// inline); weights from packed [ci][27][16] table via uniform scalar loads.
// ---------------------------------------------------------------------------
template<bool NORM>
__global__ __launch_bounds__(256)
void conv3d_kernel(const float* __restrict__ in, const float* __restrict__ cw,
                   const float* __restrict__ bias, const float* __restrict__ stats,
                   float* __restrict__ out, int relu) {
    __shared__ float xin[CIN][3][256];      // 48 KB
    int blk = blockIdx.x;
    int b = blk >> 6, t = (blk >> 1) & 31, half = blk & 1;
    int tid = threadIdx.x;

    for (int i = tid; i < CIN * 3 * 256; i += 256) {
        int hw = i & 255, r = i >> 8;
        int kt = r % 3, ci = r / 3;
        int tt = t + kt - 1;
        float v = 0.f;
        if ((unsigned)tt < TT) {
            v = in[((size_t)(b * CIN + ci) * TT + tt) * 256 + hw];
            if constexpr (NORM) {
                float mu = stats[(b * CIN + ci) * 2];
                float rs = stats[(b * CIN + ci) * 2 + 1];
                v = fmaxf((v - mu) * rs, 0.f);
            }
        }
        xin[ci][kt][hw] = v;
    }
    __syncthreads();

    int h = tid >> 4, wx = tid & 15;
    f32x4 a0 = *(const f32x4*)&bias[half * 8];
    f32x4 a1 = *(const f32x4*)&bias[half * 8 + 4];

    for (int ci = 0; ci < CIN; ++ci) {
        #pragma unroll
        for (int kt = 0; kt < 3; ++kt) {
            #pragma unroll
            for (int kh = 0; kh < 3; ++kh) {
                int h2 = h + kh - 1;
                bool vh = (unsigned)h2 < HH;
                int h2c = vh ? h2 : 0;
                #pragma unroll
                for (int kw = 0; kw < 3; ++kw) {
                    int w2 = wx + kw - 1;
                    bool v = vh && ((unsigned)w2 < WW);
                    int w2c = ((unsigned)w2 < WW) ? w2 : 0;
                    float xv = xin[ci][kt][h2c * 16 + w2c];
                    xv = v ? xv : 0.f;
                    const float* wp = cw + (size_t)(ci * 27 + kt * 9 + kh * 3 + kw) * 16 + half * 8;
                    f32x4 w0 = *(const f32x4*)(wp);
                    f32x4 w1 = *(const f32x4*)(wp + 4);
                    a0 += xv * w0; a1 += xv * w1;
                }
            }
        }
    }
    float accs[8];
    #pragma unroll
    for (int i = 0; i < 4; ++i) { accs[i] = a0[i]; accs[4 + i] = a1[i]; }
    #pragma unroll
    for (int o = 0; o < 8; ++o) {
        float v = accs[o];
        if (relu) v = fmaxf(v, 0.f);
        out[((size_t)(b * COUT + half * 8 + o) * TT + t) * 256 + tid] = v;
    }
}

// ---------------------------------------------------------------------------
// instance-norm stats per (b,c): stats[bc] = {mu, rsqrt(var+eps)}. 128 blocks.
// ---------------------------------------------------------------------------
__global__ void inorm_stats_kernel(const float* __restrict__ y, float* __restrict__ stats) {
    __shared__ float s1[256], s2[256];
    const float* p = y + (size_t)blockIdx.x * SPAT;
    float sum = 0.f, sq = 0.f;
    for (int i = threadIdx.x; i < SPAT; i += 256) {
        float v = p[i];
        sum += v; sq += v * v;
    }
    s1[threadIdx.x] = sum; s2[threadIdx.x] = sq;
    __syncthreads();
    for (int s = 128; s > 0; s >>= 1) {
        if (threadIdx.x < s) { s1[threadIdx.x] += s1[threadIdx.x + s]; s2[threadIdx.x] += s2[threadIdx.x + s]; }
        __syncthreads();
    }
    if (threadIdx.x == 0) {
        float mu = s1[0] / (float)SPAT;
        float var = s2[0] / (float)SPAT - mu * mu;
        stats[blockIdx.x * 2]     = mu;
        stats[blockIdx.x * 2 + 1] = rsqrtf(var + 1e-5f);
    }
}

// ---------------------------------------------------------------------------
// final combine: h reconstructed from the u32 slots (bf2f(hi)+bf2f(lo))
// ---------------------------------------------------------------------------
__global__ void combine_kernel(const unsigned* __restrict__ hfr,
                               const float* __restrict__ out3d,
                               const float* __restrict__ attn_w,
                               const float* __restrict__ attn_b,
                               float* __restrict__ out) {
    int idx = blockIdx.x * 256 + threadIdx.x;
    int hw = idx & 255;
    int t  = (idx >> 8) & 31;
    int b  = idx >> 13;
    float dot = attn_b[0];
    float sv[16], ov[16];
    #pragma unroll
    for (int ch = 0; ch < 16; ++ch) {
        int d = ch * 256 + hw;
        int head = d >> 10, o_h = d & 1023;
        size_t slot = (size_t)t * 32768 + (size_t)head * 8192
                    + (o_h >> 5) * 256 + b * 32 + (o_h & 31);
        unsigned v32 = hfr[slot];
        float s = bf2f((ushort_t)(v32 & 0xffffu)) + bf2f((ushort_t)(v32 >> 16));
        float o3 = out3d[(((size_t)(b * COUT + ch) * TT + t)) * 256 + hw];
        sv[ch] = s; ov[ch] = o3;
        dot += attn_w[ch] * s + attn_w[16 + ch] * o3;
    }
    float alpha = 1.f / (1.f + expf(-dot));
    #pragma unroll
    for (int ch = 0; ch < 16; ++ch) {
        out[(((size_t)(b * COUT + ch) * TT + t)) * 256 + hw] =
            alpha * ov[ch] + (1.f - alpha) * sv[ch];
    }
}

// ---------------------------------------------------------------------------
extern "C" void kernel_launch(void* const* d_in, const int* in_sizes, int n_in,
                              void* d_out, int out_size, void* d_ws, size_t ws_size,
                              hipStream_t stream) {
    const float* x      = (const float*)d_in[0];
    const float* c1_w   = (const float*)d_in[1];
    const float* c1_b   = (const float*)d_in[2];
    const float* c2_w   = (const float*)d_in[3];
    const float* c2_b   = (const float*)d_in[4];
    const float* c3_w   = (const float*)d_in[5];
    const float* c3_b   = (const float*)d_in[6];
    const float* pre_w  = (const float*)d_in[7];
    const float* pre_b  = (const float*)d_in[8];
    const float* lstm_W = (const float*)d_in[9];
    const float* lstm_b = (const float*)d_in[10];
    const float* lstm_R = (const float*)d_in[11];
    const float* attn_w = (const float*)d_in[12];
    const float* attn_b = (const float*)d_in[13];
    float* out = (float*)d_out;

    // workspace carve (all 16B aligned)
    float* wsf = (float*)d_ws;
    float* y1    = wsf;                // 1048576 f32
    float* y2    = y1 + 1048576;       // 1048576 f32
    float* out3d = y2 + 1048576;       // 1048576 f32
    float* Gx    = out3d + 1048576;    // 4194304 f32
    float* cw1   = Gx + 4194304;       // 6912 f32
    float* cw2   = cw1 + 6912;         // 6912 f32
    float* cw3   = cw2 + 6912;         // 6912 f32
    float* stats = cw3 + 6912;         // 256 f32
    float* pad   = stats + 256;
    ushort_t* xt   = (ushort_t*)(pad + 64);       // 1048576 bf16
    ushort_t* xs2b = xt + 1048576;                // 1048576 bf16
    unsigned* hfr  = (unsigned*)(xs2b + 1048576); // 1048576 u32 (4 MB)
    int*     flags = (int*)(hfr + 1048576);       // 8192 ints (32 KB)

    // zero sync flags (hfr slots are written before they are read)
    hipMemsetAsync(flags, 0, 8192 * sizeof(int), stream);

    // packs
    pack_xt_kernel<<<1024, 256, 0, stream>>>(x, xt);
    pack_cw_kernel<<<81, 256, 0, stream>>>(c1_w, c2_w, c3_w, cw1, cw2, cw3);

    // convs (split-o: 512 blocks each); inorm folded into conv2 staging
    conv3d_kernel<false><<<512, 256, 0, stream>>>(x, cw1, c1_b, nullptr, y1, 0);
    inorm_stats_kernel<<<128, 256, 0, stream>>>(y1, stats);
    conv3d_kernel<true><<<512, 256, 0, stream>>>(y1, cw2, c2_b, stats, y2, 1);
    conv3d_kernel<false><<<512, 256, 0, stream>>>(y2, cw3, c3_b, nullptr, out3d, 1);

    // pre-projection -> xs2 (bf16), BN=16 => 256 blocks
    mfma_gemm_kernel<16, true><<<DOUT / 16, 256, 0, stream>>>(
        xt, pre_w, pre_b, xs2b, DOUT, DIN);
    // gate projection -> Gx (fp32), BN=32 => 512 blocks (2/CU)
    mfma_gemm_kernel<32, false><<<4 * DOUT / 32, 256, 0, stream>>>(
        xs2b, lstm_W, lstm_b, Gx, 4 * DOUT, DOUT);

    // recurrence: one persistent kernel, block-level flag sync
    lstm_persist_kernel<<<256, 256, 0, stream>>>(lstm_R, Gx, hfr, flags);

    // combine (reads h from slots)
    combine_kernel<<<256, 256, 0, stream>>>(hfr, out3d, attn_w, attn_b, out);
}

// Round 14
// 586.474 us; speedup vs baseline: 1.2598x; 1.0063x over previous
//
#include <hip/hip_runtime.h>
#include <hip/hip_bf16.h>
#include <cstddef>

// Problem constants
#define BB   8
#define CIN  16
#define COUT 16
#define TT   32
#define HH   16
#define WW   16
#define DIN  4096
#define DOUT 4096
#define NH   4
#define DH   1024
#define SPAT 8192            // T*H*W
#define NSEQ 256             // B*T

typedef __attribute__((ext_vector_type(8))) short  bf16x8;
typedef __attribute__((ext_vector_type(4))) float  f32x4;
typedef __attribute__((ext_vector_type(4))) unsigned short us4;
typedef __attribute__((ext_vector_type(4))) int    i32x4;
typedef unsigned short ushort_t;
typedef unsigned long long u64_t;

static __device__ __forceinline__ ushort_t f2bf(float f) {
    union { float f; unsigned u; } v; v.f = f;
    unsigned r = (v.u + 0x7fffu + ((v.u >> 16) & 1u)) >> 16;
    return (ushort_t)r;
}
static __device__ __forceinline__ float bf2f(ushort_t u) {
    union { unsigned u; float f; } v; v.u = ((unsigned)u) << 16;
    return v.f;
}

// ---------------------------------------------------------------------------
// setup: pack x -> xt (bf16 seq layout) | pack 3 conv weight sets | zero flags
// grid 1113 blocks x 256
// ---------------------------------------------------------------------------
__global__ void setup_kernel(const float* __restrict__ x, ushort_t* __restrict__ xt,
                             const float* __restrict__ w1, const float* __restrict__ w2,
                             const float* __restrict__ w3,
                             float* __restrict__ cw1, float* __restrict__ cw2,
                             float* __restrict__ cw3, int* __restrict__ flags) {
    int bid = blockIdx.x;
    if (bid < 1024) {
        int idx = bid * 256 + threadIdx.x;
        int n = idx >> 10, k4 = (idx & 1023) * 4;
        int b = n >> 5, t = n & 31, c = k4 >> 8, hw = k4 & 255;
        f32x4 f = *(const f32x4*)&x[(((size_t)(b * CIN + c) * TT + t)) * 256 + hw];
        us4 o;
        #pragma unroll
        for (int i = 0; i < 4; ++i) o[i] = f2bf(f[i]);
        *(us4*)&xt[(size_t)n * DIN + k4] = o;
    } else if (bid < 1105) {
        int i = (bid - 1024) * 256 + threadIdx.x;
        if (i < 3 * 6912) {
            int set = i / 6912, j = i - set * 6912;
            const float* w = (set == 0) ? w1 : (set == 1) ? w2 : w3;
            float* cw      = (set == 0) ? cw1 : (set == 1) ? cw2 : cw3;
            int o = j & 15, r = j >> 4;
            int k = r % 27, ci = r / 27;
            cw[j] = w[(size_t)(o * CIN + ci) * 27 + k];
        }
    } else {
        int j = (bid - 1105) * 256 + threadIdx.x;   // 0..2047, int4 each
        ((i32x4*)flags)[j] = (i32x4){0, 0, 0, 0};
    }
}

// ---------------------------------------------------------------------------
// MFMA GEMM, single M-tile: C[256][N] = A[256][K](bf16) * B[N][K]^T(fp32) (+bias)
// BM=256, BN template, BK=64; 256 threads (4 waves), dbuf LDS.
// Split-K via gridDim.y: each y-slice covers K/gridDim.y and writes its own
// partial C buffer at offset y*256*N. B read exactly once from HBM.
// ---------------------------------------------------------------------------
template<int BN, bool OUT_BF16, bool ADD_BIAS>
__global__ __launch_bounds__(256, 2)
void mfma_gemm_kernel(const ushort_t* __restrict__ A, const float* __restrict__ B,
                      const float* __restrict__ bias, void* __restrict__ C,
                      int N, int K) {
    constexpr int NF  = BN / 16;          // N fragments per wave
    constexpr int TPR = 256 / BN;         // threads per B row
    constexpr int FPT = 64 / TPR;         // floats per thread per stageB
    __shared__ ushort_t Al[2][256][64];   // 64 KB
    __shared__ ushort_t Bl[2][BN][64];
    int tid  = threadIdx.x;
    int lane = tid & 63;
    int wv   = tid >> 6;       // 0..3 : wave owns rows [wv*64, wv*64+64)
    int n0 = blockIdx.x * BN;
    int ksp = K / gridDim.y;
    int kS  = blockIdx.y * ksp;

    f32x4 acc[4][NF];
    #pragma unroll
    for (int i = 0; i < 4; ++i)
        #pragma unroll
        for (int j = 0; j < NF; ++j) acc[i][j] = (f32x4){0.f, 0.f, 0.f, 0.f};

    auto stageA = [&](int buf, int k0) {
        #pragma unroll
        for (int q = 0; q < 8; ++q) {
            int row = wv * 64 + q * 8 + (lane >> 3);
            const ushort_t* g = A + (size_t)row * K + k0 + (lane & 7) * 8;
            __builtin_amdgcn_global_load_lds(
                (const __attribute__((address_space(1))) void*)g,
                (__attribute__((address_space(3))) void*)&Al[buf][wv * 64 + q * 8][0],
                16, 0, 0);
        }
    };
    auto stageB = [&](int buf, int k0) {
        int r  = tid / TPR;               // 0..BN-1
        int cs = (tid % TPR) * FPT;       // start col
        const float* g = B + (size_t)(n0 + r) * K + k0 + cs;
        #pragma unroll
        for (int q = 0; q < FPT / 4; ++q) {
            f32x4 f = *(const f32x4*)(g + q * 4);
            us4 pk;
            #pragma unroll
            for (int e = 0; e < 4; ++e) pk[e] = f2bf(f[e]);
            *(us4*)&Bl[buf][r][cs + q * 4] = pk;
        }
    };
    auto compute = [&](int buf) {
        #pragma unroll
        for (int ks = 0; ks < 2; ++ks) {
            bf16x8 af[4], bfr[NF];
            #pragma unroll
            for (int i = 0; i < 4; ++i)
                af[i] = *(const bf16x8*)&Al[buf][wv * 64 + i * 16 + (lane & 15)][ks * 32 + (lane >> 4) * 8];
            #pragma unroll
            for (int j = 0; j < NF; ++j)
                bfr[j] = *(const bf16x8*)&Bl[buf][j * 16 + (lane & 15)][ks * 32 + (lane >> 4) * 8];
            #pragma unroll
            for (int i = 0; i < 4; ++i)
                #pragma unroll
                for (int j = 0; j < NF; ++j)
                    acc[i][j] = __builtin_amdgcn_mfma_f32_16x16x32_bf16(af[i], bfr[j], acc[i][j], 0, 0, 0);
        }
    };

    stageA(0, kS); stageB(0, kS);
    __syncthreads();
    int nk = ksp / 64;
    int cur = 0;
    for (int t = 0; t < nk; ++t) {
        if (t + 1 < nk) { stageA(cur ^ 1, kS + (t + 1) * 64); stageB(cur ^ 1, kS + (t + 1) * 64); }
        compute(cur);
        __syncthreads();
        cur ^= 1;
    }

    size_t cofs = (size_t)blockIdx.y * 256 * N;
    #pragma unroll
    for (int i = 0; i < 4; ++i) {
        int row = wv * 64 + i * 16 + (lane >> 4) * 4;
        #pragma unroll
        for (int j = 0; j < NF; ++j) {
            int col = n0 + j * 16 + (lane & 15);
            float bv = ADD_BIAS ? bias[col] : 0.f;
            #pragma unroll
            for (int r = 0; r < 4; ++r) {
                float v = acc[i][j][r] + bv;
                if constexpr (OUT_BF16) ((ushort_t*)C)[cofs + (size_t)(row + r) * N + col] = f2bf(v);
                else                    ((float*)C)[cofs + (size_t)(row + r) * N + col] = v;
            }
        }
    }
}

// ---------------------------------------------------------------------------
// Persistent sLSTM (best-known sync):
//  - R (fp32) staged directly into LDS in MFMA fragment order, once.
//  - h via hfr u32 slots [t][head][ks][b][k'] = (lo<<16|hi) bf16 pair; relaxed
//    agent atomics (LLC-coherent, no cache-wide fences).
//  - flags[t][head][oc]: tid0 stores after __syncthreads (vmcnt drained);
//    consumers poll the 64 flags of their head with one coalesced lane-load.
//  - Gx comes as two split-K partials (GxA,GxB); lstm_b added here (hoisted).
// grid: 256 blocks = head(4) x ochunk(64 of 16 o's), 256 threads, 1 block/CU.
// ---------------------------------------------------------------------------
__global__ __launch_bounds__(256, 1)
void lstm_persist_kernel(const float* __restrict__ R,       // [4][4][1024][1024] fp32
                         const float* __restrict__ GxA,     // [256][16384] partial
                         const float* __restrict__ GxB,     // [256][16384] partial
                         const float* __restrict__ lstm_b,  // [4][4096]
                         unsigned* __restrict__ hfr,        // [32][4][32][8][32] u32
                         int* __restrict__ flags) {         // [32][4][64], zeroed
    __shared__ ushort_t Rl[4][32][64 * 8];   // [gate][ks][lane*8] = 128 KB
    __shared__ float gh_p[4][4][16][8];      // [wave][gate][o_l][b] = 8 KB

    int tid  = threadIdx.x;
    int lane = tid & 63;
    int w    = tid >> 6;               // wave = K-chunk (ks in [w*8, w*8+8))
    int head = blockIdx.x >> 6;
    int oc   = blockIdx.x & 63;

    // ---- stage R slice fp32 -> bf16 LDS in fragment order, once ----
    #pragma unroll 4
    for (int n = 0; n < 64; ++n) {
        int g = n >> 4, r = n & 15;
        const float* src = R + ((size_t)((head * 4 + g) * DH + oc * 16 + r)) * DH + tid * 4;
        f32x4 f = *(const f32x4*)src;
        int k0 = tid * 4;
        int ks = k0 >> 5;
        int kI = (k0 >> 3) & 3;
        int e8 = k0 & 7;               // 0 or 4
        union { ushort_t u[4]; u64_t q; } pk;
        #pragma unroll
        for (int e = 0; e < 4; ++e) pk.u[e] = f2bf(f[e]);
        *(u64_t*)&Rl[g][ks][((kI << 4) | r) * 8 + e8] = pk.q;
    }

    int arow = lane & 15;          // packed-B column (part,bb); also D column
    int part = arow >> 3;          // 0: hi half of h, 1: lo half
    int bb   = arow & 7;           // batch
    int kseg = lane >> 4;          // 0..3

    // gate-phase identity (tid < 128)
    int gb  = tid >> 4;            // batch
    int gol = tid & 15;            // o_local
    int gd  = head * DH + oc * 16 + gol;
    int o_h = oc * 16 + gol;       // o within head (= k index for next step)
    unsigned hslot = ((unsigned)head * 32 + (o_h >> 5)) * 256 + gb * 32 + (o_h & 31);
    float c_r = 0.f, n_r = 0.f, m_r = 0.f;
    float lb0 = 0.f, lb1 = 0.f, lb2 = 0.f, lb3 = 0.f;
    if (tid < 128) {
        lb0 = lstm_b[gd];
        lb1 = lstm_b[DOUT + gd];
        lb2 = lstm_b[2 * DOUT + gd];
        lb3 = lstm_b[3 * DOUT + gd];
    }

    __syncthreads();

    for (int t = 0; t < TT; ++t) {
        // prefetch this step's Gx partials (h-independent) before the flag wait
        float gx0 = 0.f, gx1 = 0.f, gx2 = 0.f, gx3 = 0.f;
        if (tid < 128) {
            size_t gxoff = ((size_t)(gb * TT + t)) * (4 * DOUT) + gd;
            gx0 = GxA[gxoff]            + GxB[gxoff]            + lb0;
            gx1 = GxA[gxoff + DOUT]     + GxB[gxoff + DOUT]     + lb1;
            gx2 = GxA[gxoff + 2 * DOUT] + GxB[gxoff + 2 * DOUT] + lb2;
            gx3 = GxA[gxoff + 3 * DOUT] + GxB[gxoff + 3 * DOUT] + lb3;
        }

        if (t > 0) {
            // coalesced lane-parallel poll of this head's 64 producer flags
            const int* fl = flags + (((t - 1) * 4 + head) << 6);
            for (;;) {
                int v = __hip_atomic_load(fl + lane, __ATOMIC_RELAXED,
                                          __HIP_MEMORY_SCOPE_AGENT);
                if (__all(v != 0)) break;
                __builtin_amdgcn_s_sleep(1);
            }

            // load h fragments (B-operand layout) as u64 atomic loads
            const u64_t* hb = (const u64_t*)hfr
                + ((((size_t)(t - 1) * 4 + head) * 32) * 256 + bb * 32 + kseg * 8) / 2;
            bf16x8 hf[8];
            #pragma unroll
            for (int j = 0; j < 8; ++j) {
                const u64_t* p = hb + (size_t)(w * 8 + j) * 128;
                union { ushort_t u[8]; bf16x8 v; } fr;
                #pragma unroll
                for (int e2 = 0; e2 < 4; ++e2) {
                    u64_t q = __hip_atomic_load(p + e2, __ATOMIC_RELAXED,
                                                __HIP_MEMORY_SCOPE_AGENT);
                    unsigned q0 = (unsigned)q, q1 = (unsigned)(q >> 32);
                    fr.u[e2 * 2]     = part ? (ushort_t)(q0 >> 16) : (ushort_t)(q0 & 0xffffu);
                    fr.u[e2 * 2 + 1] = part ? (ushort_t)(q1 >> 16) : (ushort_t)(q1 & 0xffffu);
                }
                hf[j] = fr.v;
            }

            f32x4 acc[4];
            #pragma unroll
            for (int g = 0; g < 4; ++g) acc[g] = (f32x4){0.f, 0.f, 0.f, 0.f};
            #pragma unroll
            for (int g = 0; g < 4; ++g)
                #pragma unroll
                for (int j = 0; j < 8; ++j) {
                    bf16x8 a = *(const bf16x8*)&Rl[g][w * 8 + j][lane * 8];
                    acc[g] = __builtin_amdgcn_mfma_f32_16x16x32_bf16(a, hf[j], acc[g], 0, 0, 0);
                }
            // fold hi+lo halves (partner column = col^8 -> lane^8)
            #pragma unroll
            for (int g = 0; g < 4; ++g)
                #pragma unroll
                for (int r = 0; r < 4; ++r)
                    acc[g][r] += __shfl_xor(acc[g][r], 8, 64);
            // D layout: col = lane&15, row = kseg*4 + r
            if (part == 0) {
                int orow0 = kseg * 4;
                #pragma unroll
                for (int g = 0; g < 4; ++g)
                    #pragma unroll
                    for (int r = 0; r < 4; ++r)
                        gh_p[w][g][orow0 + r][bb] = acc[g][r];
            }
        } else {
            for (int i = tid; i < 4 * 4 * 16 * 8; i += 256)
                ((float*)gh_p)[i] = 0.f;
        }
        __syncthreads();

        if (tid < 128) {
            float ip = gx0 +
                gh_p[0][0][gol][gb] + gh_p[1][0][gol][gb] + gh_p[2][0][gol][gb] + gh_p[3][0][gol][gb];
            float fp = gx1 +
                gh_p[0][1][gol][gb] + gh_p[1][1][gol][gb] + gh_p[2][1][gol][gb] + gh_p[3][1][gol][gb];
            float zp = gx2 +
                gh_p[0][2][gol][gb] + gh_p[1][2][gol][gb] + gh_p[2][2][gol][gb] + gh_p[3][2][gol][gb];
            float op = gx3 +
                gh_p[0][3][gol][gb] + gh_p[1][3][gol][gb] + gh_p[2][3][gol][gb] + gh_p[3][3][gol][gb];
            float mn = fmaxf(fp + m_r, ip);
            float iv = __expf(ip - mn);
            float fv = __expf(fp + m_r - mn);
            float zc = fminf(fmaxf(zp, -9.f), 9.f);
            float th = 1.f - 2.f / (__expf(2.f * zc) + 1.f);
            c_r = fv * c_r + iv * th;
            n_r = fv * n_r + iv;
            float sig = 1.f / (1.f + __expf(-op));
            float hv = sig * c_r / n_r;
            m_r = mn;
            unsigned hi = f2bf(hv);
            unsigned lo = f2bf(hv - bf2f((ushort_t)hi));
            __hip_atomic_store(&hfr[(size_t)t * 32768 + hslot],
                               hi | (lo << 16),
                               __ATOMIC_RELAXED, __HIP_MEMORY_SCOPE_AGENT);
        }
        __syncthreads();   // drains this block's stores (vmcnt) before signal
        if (tid == 0)
            __hip_atomic_store(&flags[((t * 4 + head) << 6) + oc], 1,
                               __ATOMIC_RELAXED, __HIP_MEMORY_SCOPE_AGENT);
    }
}

// ---------------------------------------------------------------------------
// conv3d 3x3x3 pad=1, split-o: 512 blocks = (b,t,half); 8 out-channels/block.
// x slice in LDS (optionally instance-norm+relu inline); weights via packed
// [ci][27][16] table (uniform scalar loads). PSUM: emit per-slice sum/sumsq.
// ---------------------------------------------------------------------------
template<bool NORM, bool PSUM>
__global__ __launch_bounds__(256)
void conv3d_kernel(const float* __restrict__ in, const float* __restrict__ cw,
                   const float* __restrict__ bias, const float* __restrict__ stats,
                   float* __restrict__ out, float* __restrict__ psum, int relu) {
    __shared__ float xin[CIN][3][256];      // 48 KB
    int blk = blockIdx.x;
    int b = blk >> 6, t = (blk >> 1) & 31, half = blk & 1;
    int tid = threadIdx.x;

    for (int i = tid; i < CIN * 3 * 256; i += 256) {
        int hw = i & 255, r = i >> 8;
        int kt = r % 3, ci = r / 3;
        int tt = t + kt - 1;
        float v = 0.f;
        if ((unsigned)tt < TT) {
            v = in[((size_t)(b * CIN + ci) * TT + tt) * 256 + hw];
            if constexpr (NORM) {
                float mu = stats[(b * CIN + ci) * 2];
                float rs = stats[(b * CIN + ci) * 2 + 1];
                v = fmaxf((v - mu) * rs, 0.f);
            }
        }
        xin[ci][kt][hw] = v;
    }
    __syncthreads();

    int h = tid >> 4, wx = tid & 15;
    f32x4 a0 = *(const f32x4*)&bias[half * 8];
    f32x4 a1 = *(const f32x4*)&bias[half * 8 + 4];

    for (int ci = 0; ci < CIN; ++ci) {
        #pragma unroll
        for (int kt = 0; kt < 3; ++kt) {
            #pragma unroll
            for (int kh = 0; kh < 3; ++kh) {
                int h2 = h + kh - 1;
                bool vh = (unsigned)h2 < HH;
                int h2c = vh ? h2 : 0;
                #pragma unroll
                for (int kw = 0; kw < 3; ++kw) {
                    int w2 = wx + kw - 1;
                    bool v = vh && ((unsigned)w2 < WW);
                    int w2c = ((unsigned)w2 < WW) ? w2 : 0;
                    float xv = xin[ci][kt][h2c * 16 + w2c];
                    xv = v ? xv : 0.f;
                    const float* wp = cw + (size_t)(ci * 27 + kt * 9 + kh * 3 + kw) * 16 + half * 8;
                    f32x4 w0 = *(const f32x4*)(wp);
                    f32x4 w1 = *(const f32x4*)(wp + 4);
                    a0 += xv * w0; a1 += xv * w1;
                }
            }
        }
    }
    float accs[8];
    #pragma unroll
    for (int i = 0; i < 4; ++i) { accs[i] = a0[i]; accs[4 + i] = a1[i]; }
    #pragma unroll
    for (int o = 0; o < 8; ++o) {
        float v = accs[o];
        if (relu) v = fmaxf(v, 0.f);
        out[((size_t)(b * COUT + half * 8 + o) * TT + t) * 256 + tid] = v;
    }

    if constexpr (PSUM) {
        __syncthreads();                 // xin no longer needed; reuse as scratch
        float* sm = (float*)xin;         // 64 floats used
        int wv = tid >> 6;
        #pragma unroll
        for (int o = 0; o < 8; ++o) {
            float s = accs[o];
            float q = accs[o] * accs[o];
            #pragma unroll
            for (int m = 1; m < 64; m <<= 1) {
                s += __shfl_xor(s, m, 64);
                q += __shfl_xor(q, m, 64);
            }
            if ((tid & 63) == 0) { sm[wv * 16 + o * 2] = s; sm[wv * 16 + o * 2 + 1] = q; }
        }
        __syncthreads();
        if (tid < 16) {
            int o = tid >> 1, which = tid & 1;
            float v = sm[o * 2 + which] + sm[16 + o * 2 + which]
                    + sm[32 + o * 2 + which] + sm[48 + o * 2 + which];
            psum[((((size_t)(b * 32 + t) * 2 + half) * 8 + o) * 2) + which] = v;
        }
    }
}

// ---------------------------------------------------------------------------
// instance-norm stats from conv1 partial sums. 1 block x 256 (128 active).
// stats[bc] = {mu, rsqrt(var+eps)}
// ---------------------------------------------------------------------------
__global__ void inorm_stats_kernel(const float* __restrict__ psum, float* __restrict__ stats) {
    int tid = threadIdx.x;
    if (tid < 128) {
        int b = tid >> 4, c = tid & 15;
        int half = c >> 3, ch = c & 7;
        float sum = 0.f, sq = 0.f;
        for (int t = 0; t < TT; ++t) {
            size_t base = (((size_t)(b * 32 + t) * 2 + half) * 8 + ch) * 2;
            sum += psum[base];
            sq  += psum[base + 1];
        }
        float mu = sum / (float)SPAT;
        float var = sq / (float)SPAT - mu * mu;
        stats[(b * CIN + c) * 2]     = mu;
        stats[(b * CIN + c) * 2 + 1] = rsqrtf(var + 1e-5f);
    }
}

// ---------------------------------------------------------------------------
// final combine: h reconstructed from the u32 slots (bf2f(hi)+bf2f(lo))
// ---------------------------------------------------------------------------
__global__ void combine_kernel(const unsigned* __restrict__ hfr,
                               const float* __restrict__ out3d,
                               const float* __restrict__ attn_w,
                               const float* __restrict__ attn_b,
                               float* __restrict__ out) {
    int idx = blockIdx.x * 256 + threadIdx.x;
    int hw = idx & 255;
    int t  = (idx >> 8) & 31;
    int b  = idx >> 13;
    float dot = attn_b[0];
    float sv[16], ov[16];
    #pragma unroll
    for (int ch = 0; ch < 16; ++ch) {
        int d = ch * 256 + hw;
        int head = d >> 10, o_h = d & 1023;
        size_t slot = (size_t)t * 32768 + (size_t)head * 8192
                    + (o_h >> 5) * 256 + b * 32 + (o_h & 31);
        unsigned v32 = hfr[slot];
        float s = bf2f((ushort_t)(v32 & 0xffffu)) + bf2f((ushort_t)(v32 >> 16));
        float o3 = out3d[(((size_t)(b * COUT + ch) * TT + t)) * 256 + hw];
        sv[ch] = s; ov[ch] = o3;
        dot += attn_w[ch] * s + attn_w[16 + ch] * o3;
    }
    float alpha = 1.f / (1.f + expf(-dot));
    #pragma unroll
    for (int ch = 0; ch < 16; ++ch) {
        out[(((size_t)(b * COUT + ch) * TT + t)) * 256 + hw] =
            alpha * ov[ch] + (1.f - alpha) * sv[ch];
    }
}

// ---------------------------------------------------------------------------
extern "C" void kernel_launch(void* const* d_in, const int* in_sizes, int n_in,
                              void* d_out, int out_size, void* d_ws, size_t ws_size,
                              hipStream_t stream) {
    const float* x      = (const float*)d_in[0];
    const float* c1_w   = (const float*)d_in[1];
    const float* c1_b   = (const float*)d_in[2];
    const float* c2_w   = (const float*)d_in[3];
    const float* c2_b   = (const float*)d_in[4];
    const float* c3_w   = (const float*)d_in[5];
    const float* c3_b   = (const float*)d_in[6];
    const float* pre_w  = (const float*)d_in[7];
    const float* pre_b  = (const float*)d_in[8];
    const float* lstm_W = (const float*)d_in[9];
    const float* lstm_b = (const float*)d_in[10];
    const float* lstm_R = (const float*)d_in[11];
    const float* attn_w = (const float*)d_in[12];
    const float* attn_b = (const float*)d_in[13];
    float* out = (float*)d_out;

    // workspace carve (all 16B aligned)
    float* wsf = (float*)d_ws;
    float* y1    = wsf;                // 1048576 f32
    float* y2    = y1 + 1048576;       // 1048576 f32
    float* out3d = y2 + 1048576;       // 1048576 f32
    float* GxA   = out3d + 1048576;    // 4194304 f32 (split-K partial 0)
    float* GxB   = GxA + 4194304;      // 4194304 f32 (split-K partial 1)
    float* cw1   = GxB + 4194304;      // 6912 f32
    float* cw2   = cw1 + 6912;         // 6912 f32
    float* cw3   = cw2 + 6912;         // 6912 f32
    float* stats = cw3 + 6912;         // 256 f32
    float* psum  = stats + 256;        // 8192 f32
    float* pad   = psum + 8192;
    ushort_t* xt   = (ushort_t*)(pad + 64);       // 1048576 bf16
    ushort_t* xs2b = xt + 1048576;                // 1048576 bf16
    unsigned* hfr  = (unsigned*)(xs2b + 1048576); // 1048576 u32 (4 MB)
    int*     flags = (int*)(hfr + 1048576);       // 8192 ints (32 KB)

    // setup: pack xt + pack conv weights + zero flags (one dispatch)
    setup_kernel<<<1113, 256, 0, stream>>>(x, xt, c1_w, c2_w, c3_w, cw1, cw2, cw3, flags);

    // convs (split-o: 512 blocks each); conv1 emits psum; inorm folded into conv2
    conv3d_kernel<false, true><<<512, 256, 0, stream>>>(x, cw1, c1_b, nullptr, y1, psum, 0);
    inorm_stats_kernel<<<1, 256, 0, stream>>>(psum, stats);
    conv3d_kernel<true, false><<<512, 256, 0, stream>>>(y1, cw2, c2_b, stats, y2, nullptr, 1);
    conv3d_kernel<false, false><<<512, 256, 0, stream>>>(y2, cw3, c3_b, nullptr, out3d, nullptr, 1);

    // pre-projection -> xs2 (bf16), BN=16, 256 blocks, full K
    mfma_gemm_kernel<16, true, true><<<dim3(DOUT / 16, 1), 256, 0, stream>>>(
        xt, pre_w, pre_b, xs2b, DOUT, DIN);
    // gate projection -> Gx partials (fp32), BN=32, split-K x2 => 1024 blocks
    mfma_gemm_kernel<32, false, false><<<dim3(4 * DOUT / 32, 2), 256, 0, stream>>>(
        xs2b, lstm_W, nullptr, GxA, 4 * DOUT, DOUT);

    // recurrence: one persistent kernel, block-level flag sync
    lstm_persist_kernel<<<256, 256, 0, stream>>>(lstm_R, GxA, GxB, lstm_b, hfr, flags);

    // combine (reads h from slots)
    combine_kernel<<<256, 256, 0, stream>>>(hfr, out3d, attn_w, attn_b, out);
}